// Round 1
// 579.485 us; speedup vs baseline: 1.1789x; 1.1789x over previous
//
#include <hip/hip_runtime.h>
#include <hip/hip_fp16.h>

#define TWO_PI 6.283185307179586f
#define PI_F   3.14159265358979f

// Problem constants
#define HH 128      // H
#define WW 128      // W
#define FN 256      // padded FFT size (2H)
#define NF 129      // FN/2+1 vertical frequency bins
#define CC 96
#define BB 16

#define SCL_DN 0.0009765625f   // 2^-10 : scale on row-conv output before fp16 store
#define SCL_UP 1024.0f

typedef unsigned int uint2v __attribute__((ext_vector_type(2)));

__device__ __forceinline__ float2 cmul(float2 a, float2 b){
  return make_float2(a.x*b.x - a.y*b.y, a.x*b.y + a.y*b.x);
}
__device__ __forceinline__ float2 cadd(float2 a, float2 b){ return make_float2(a.x+b.x, a.y+b.y); }
__device__ __forceinline__ float2 csub(float2 a, float2 b){ return make_float2(a.x-b.x, a.y-b.y); }
__device__ __forceinline__ float2 shflx(float2 v, int m){
  float2 r; r.x = __shfl_xor(v.x, m, 64); r.y = __shfl_xor(v.y, m, 64); return r;
}
__device__ __forceinline__ unsigned short f2h(float v){ return __half_as_ushort(__float2half(v)); }
__device__ __forceinline__ float h2f(unsigned short u){ return __half2float(__ushort_as_half(u)); }

// ---------------------------------------------------------------------------
// Cross-lane exchange helpers that stay on the VALU pipe (gfx950):
//   swp32/swp16: one v_permlane{32,16}_swap_b32 per 32b yields BOTH the
//   low-half value (lane l&~h) and high-half value (lane l|h) on every lane.
//   dppx<CTRL>: quad_perm DPP for xor-1 / xor-2.
// Only h=8 and h=4 stages remain ds_swizzle (LDS pipe).
// ---------------------------------------------------------------------------
__device__ __forceinline__ void swp32(float2 v, float2& lo, float2& hi){
  uint2v rx = __builtin_amdgcn_permlane32_swap(__float_as_uint(v.x), __float_as_uint(v.x), false, false);
  uint2v ry = __builtin_amdgcn_permlane32_swap(__float_as_uint(v.y), __float_as_uint(v.y), false, false);
  lo = make_float2(__uint_as_float(rx[0]), __uint_as_float(ry[0]));
  hi = make_float2(__uint_as_float(rx[1]), __uint_as_float(ry[1]));
}
__device__ __forceinline__ void swp16(float2 v, float2& lo, float2& hi){
  uint2v rx = __builtin_amdgcn_permlane16_swap(__float_as_uint(v.x), __float_as_uint(v.x), false, false);
  uint2v ry = __builtin_amdgcn_permlane16_swap(__float_as_uint(v.y), __float_as_uint(v.y), false, false);
  lo = make_float2(__uint_as_float(rx[0]), __uint_as_float(ry[0]));
  hi = make_float2(__uint_as_float(rx[1]), __uint_as_float(ry[1]));
}
template<int CTRL>
__device__ __forceinline__ float2 dppx(float2 v){
  float2 r;
  r.x = __uint_as_float((unsigned)__builtin_amdgcn_update_dpp(0, (int)__float_as_uint(v.x), CTRL, 0xF, 0xF, true));
  r.y = __uint_as_float((unsigned)__builtin_amdgcn_update_dpp(0, (int)__float_as_uint(v.y), CTRL, 0xF, 0xF, true));
  return r;
}
#define DPP_XOR1 0xB1   // quad_perm [1,0,3,2]
#define DPP_XOR2 0x4E   // quad_perm [2,3,0,1]

// ---------------------------------------------------------------------------
// Wave-resident 256-pt FFT (verified R1/R2): lane l holds positions
// l, l+64, l+128, l+192. Forward = DIF (natural in -> bit-reversed positions
// out; position j holds natural bin br8(j)). Inverse = DIT (bit-reversed in,
// natural out, crop to 0..127).
// ---------------------------------------------------------------------------
struct Tw {
  float2 w128a, w128b, w64;
  float2 wc[5];   // cross-lane twiddles for h = 32,16,8,4,2
};

__device__ __forceinline__ void tw_init(Tw& t, int l){
  float s, c;
  sincosf(-TWO_PI * (float)l * (1.0f/256.0f), &s, &c);
  t.w128a = make_float2(c, s);                 // W256^l
  t.w128b = make_float2(s, -c);                // W256^(l+64)
  t.w64   = make_float2(c*c - s*s, 2.0f*c*s);  // W256^(2l)
  const int hs[5] = {32,16,8,4,2};
#pragma unroll
  for (int i = 0; i < 5; ++i){
    int h = hs[i];
    float ang = -PI_F * (float)(l & (h-1)) / (float)h;
    sincosf(ang, &s, &c);
    t.wc[i] = make_float2(c, s);
  }
}

__device__ __forceinline__ void fft256_fwd_padded(float2& x0, float2& x1,
                                                  float2& x2, float2& x3,
                                                  const Tw& t, int l){
  x2 = cmul(x0, t.w128a);
  x3 = cmul(x1, t.w128b);
  float2 a = x0, b = x1;
  x0 = cadd(a, b); x1 = cmul(csub(a, b), t.w64);
  a = x2; b = x3;
  x2 = cadd(a, b); x3 = cmul(csub(a, b), t.w64);
  // h = 32 : permlane32_swap (VALU)
  {
    bool up = (l & 32) == 0; float2 w = t.wc[0], lo, hi;
    swp32(x0, lo, hi); x0 = up ? cadd(lo, hi) : cmul(csub(lo, hi), w);
    swp32(x1, lo, hi); x1 = up ? cadd(lo, hi) : cmul(csub(lo, hi), w);
    swp32(x2, lo, hi); x2 = up ? cadd(lo, hi) : cmul(csub(lo, hi), w);
    swp32(x3, lo, hi); x3 = up ? cadd(lo, hi) : cmul(csub(lo, hi), w);
  }
  // h = 16 : permlane16_swap (VALU)
  {
    bool up = (l & 16) == 0; float2 w = t.wc[1], lo, hi;
    swp16(x0, lo, hi); x0 = up ? cadd(lo, hi) : cmul(csub(lo, hi), w);
    swp16(x1, lo, hi); x1 = up ? cadd(lo, hi) : cmul(csub(lo, hi), w);
    swp16(x2, lo, hi); x2 = up ? cadd(lo, hi) : cmul(csub(lo, hi), w);
    swp16(x3, lo, hi); x3 = up ? cadd(lo, hi) : cmul(csub(lo, hi), w);
  }
  // h = 8, 4 : ds_swizzle
  {
    bool up = (l & 8) == 0; float2 w = t.wc[2], o;
    o = shflx(x0, 8); x0 = up ? cadd(x0, o) : cmul(csub(o, x0), w);
    o = shflx(x1, 8); x1 = up ? cadd(x1, o) : cmul(csub(o, x1), w);
    o = shflx(x2, 8); x2 = up ? cadd(x2, o) : cmul(csub(o, x2), w);
    o = shflx(x3, 8); x3 = up ? cadd(x3, o) : cmul(csub(o, x3), w);
  }
  {
    bool up = (l & 4) == 0; float2 w = t.wc[3], o;
    o = shflx(x0, 4); x0 = up ? cadd(x0, o) : cmul(csub(o, x0), w);
    o = shflx(x1, 4); x1 = up ? cadd(x1, o) : cmul(csub(o, x1), w);
    o = shflx(x2, 4); x2 = up ? cadd(x2, o) : cmul(csub(o, x2), w);
    o = shflx(x3, 4); x3 = up ? cadd(x3, o) : cmul(csub(o, x3), w);
  }
  // h = 2 : DPP quad_perm (VALU)
  {
    bool up = (l & 2) == 0; float2 w = t.wc[4], o;
    o = dppx<DPP_XOR2>(x0); x0 = up ? cadd(x0, o) : cmul(csub(o, x0), w);
    o = dppx<DPP_XOR2>(x1); x1 = up ? cadd(x1, o) : cmul(csub(o, x1), w);
    o = dppx<DPP_XOR2>(x2); x2 = up ? cadd(x2, o) : cmul(csub(o, x2), w);
    o = dppx<DPP_XOR2>(x3); x3 = up ? cadd(x3, o) : cmul(csub(o, x3), w);
  }
  // h = 1 : DPP quad_perm (VALU)
  {
    bool up = (l & 1) == 0; float2 o;
    o = dppx<DPP_XOR1>(x0); x0 = up ? cadd(x0, o) : csub(o, x0);
    o = dppx<DPP_XOR1>(x1); x1 = up ? cadd(x1, o) : csub(o, x1);
    o = dppx<DPP_XOR1>(x2); x2 = up ? cadd(x2, o) : csub(o, x2);
    o = dppx<DPP_XOR1>(x3); x3 = up ? cadd(x3, o) : csub(o, x3);
  }
}

__device__ __forceinline__ void fft256_inv_crop(float2& x0, float2& x1,
                                                float2& x2, float2& x3,
                                                const Tw& t, int l){
  // h = 1 : DPP
  {
    bool up = (l & 1) == 0; float2 o;
    o = dppx<DPP_XOR1>(x0); x0 = up ? cadd(x0, o) : csub(o, x0);
    o = dppx<DPP_XOR1>(x1); x1 = up ? cadd(x1, o) : csub(o, x1);
    o = dppx<DPP_XOR1>(x2); x2 = up ? cadd(x2, o) : csub(o, x2);
    o = dppx<DPP_XOR1>(x3); x3 = up ? cadd(x3, o) : csub(o, x3);
  }
  // h = 2 : DPP
  {
    bool up = (l & 2) == 0; float2 w = make_float2(t.wc[4].x, -t.wc[4].y), o;
    o = dppx<DPP_XOR2>(x0); x0 = up ? cadd(x0, cmul(w, o)) : csub(o, cmul(w, x0));
    o = dppx<DPP_XOR2>(x1); x1 = up ? cadd(x1, cmul(w, o)) : csub(o, cmul(w, x1));
    o = dppx<DPP_XOR2>(x2); x2 = up ? cadd(x2, cmul(w, o)) : csub(o, cmul(w, x2));
    o = dppx<DPP_XOR2>(x3); x3 = up ? cadd(x3, cmul(w, o)) : csub(o, cmul(w, x3));
  }
  // h = 4, 8 : ds_swizzle
  {
    bool up = (l & 4) == 0; float2 w = make_float2(t.wc[3].x, -t.wc[3].y), o;
    o = shflx(x0, 4); x0 = up ? cadd(x0, cmul(w, o)) : csub(o, cmul(w, x0));
    o = shflx(x1, 4); x1 = up ? cadd(x1, cmul(w, o)) : csub(o, cmul(w, x1));
    o = shflx(x2, 4); x2 = up ? cadd(x2, cmul(w, o)) : csub(o, cmul(w, x2));
    o = shflx(x3, 4); x3 = up ? cadd(x3, cmul(w, o)) : csub(o, cmul(w, x3));
  }
  {
    bool up = (l & 8) == 0; float2 w = make_float2(t.wc[2].x, -t.wc[2].y), o;
    o = shflx(x0, 8); x0 = up ? cadd(x0, cmul(w, o)) : csub(o, cmul(w, x0));
    o = shflx(x1, 8); x1 = up ? cadd(x1, cmul(w, o)) : csub(o, cmul(w, x1));
    o = shflx(x2, 8); x2 = up ? cadd(x2, cmul(w, o)) : csub(o, cmul(w, x2));
    o = shflx(x3, 8); x3 = up ? cadd(x3, cmul(w, o)) : csub(o, cmul(w, x3));
  }
  // h = 16 : permlane16_swap; x' = up ? lo + w*hi : lo - w*hi (one cmul shared)
  {
    bool up = (l & 16) == 0; float2 w = make_float2(t.wc[1].x, -t.wc[1].y), lo, hi, m;
    swp16(x0, lo, hi); m = cmul(w, hi); x0 = up ? cadd(lo, m) : csub(lo, m);
    swp16(x1, lo, hi); m = cmul(w, hi); x1 = up ? cadd(lo, m) : csub(lo, m);
    swp16(x2, lo, hi); m = cmul(w, hi); x2 = up ? cadd(lo, m) : csub(lo, m);
    swp16(x3, lo, hi); m = cmul(w, hi); x3 = up ? cadd(lo, m) : csub(lo, m);
  }
  // h = 32 : permlane32_swap
  {
    bool up = (l & 32) == 0; float2 w = make_float2(t.wc[0].x, -t.wc[0].y), lo, hi, m;
    swp32(x0, lo, hi); m = cmul(w, hi); x0 = up ? cadd(lo, m) : csub(lo, m);
    swp32(x1, lo, hi); m = cmul(w, hi); x1 = up ? cadd(lo, m) : csub(lo, m);
    swp32(x2, lo, hi); m = cmul(w, hi); x2 = up ? cadd(lo, m) : csub(lo, m);
    swp32(x3, lo, hi); m = cmul(w, hi); x3 = up ? cadd(lo, m) : csub(lo, m);
  }
  {
    float2 w = make_float2(t.w64.x, -t.w64.y);
    float2 t0 = cmul(w, x1); x1 = csub(x0, t0); x0 = cadd(x0, t0);
    float2 t1 = cmul(w, x3); x3 = csub(x2, t1); x2 = cadd(x2, t1);
  }
  {
    float2 wa = make_float2(t.w128a.x, -t.w128a.y);
    float2 wb = make_float2(t.w128b.x, -t.w128b.y);
    x0 = cadd(x0, cmul(wa, x2));
    x1 = cadd(x1, cmul(wb, x3));
  }
}

// ---------------------------------------------------------------------------
// kprep_col: grid CC*2. Block handles 64 columns of channel c. MLP computed
// inline per lane (no staging), column forward FFT, natural-bin spectrum to
// LDS, coalesced write into the FRONT HALF (v=0..127) of Khat rows.
// ---------------------------------------------------------------------------
__global__ __launch_bounds__(512) void kprep_col(const float* __restrict__ W1,
                                                 const float* __restrict__ b1,
                                                 const float* __restrict__ W2,
                                                 const float* __restrict__ b2,
                                                 float2* __restrict__ Khat){
  __shared__ float sRe[NF*65];
  __shared__ float sIm[NF*65];
  const int S = 65;
  int t = threadIdx.x, l = t & 63, w = t >> 6;
  int c  = blockIdx.x >> 1;
  int q0 = (blockIdx.x & 1) * 64;
  Tw tw; tw_init(tw, l);
  int r6 = __brev((unsigned)l) >> 26;

  float w1y[16], w1x[16], bb1[16], w2r[16];
#pragma unroll
  for (int h = 0; h < 16; ++h){
    w1y[h] = W1[h]; w1x[h] = W1[16+h]; bb1[h] = b1[h]; w2r[h] = W2[h*CC + c];
  }
  float bb2 = b2[c];
  float gy0 = (float)l        * (1.0f/127.0f);
  float gy1 = (float)(l + 64) * (1.0f/127.0f);

  for (int qi = 0; qi < 8; ++qi){
    int qq = w*8 + qi;                       // 0..63
    float gx = (float)(q0 + qq) * (1.0f/127.0f);
    float a0 = bb2, a1 = bb2;
#pragma unroll
    for (int h = 0; h < 16; ++h){
      float hx = gx*w1x[h] + bb1[h];
      a0 += fmaxf(gy0*w1y[h] + hx, 0.0f) * w2r[h];
      a1 += fmaxf(gy1*w1y[h] + hx, 0.0f) * w2r[h];
    }
    float2 x0 = make_float2(a0, 0.f);
    float2 x1 = make_float2(a1, 0.f);
    float2 x2, x3;
    fft256_fwd_padded(x0, x1, x2, x3, tw, l);
    if (r6 <= 32){ sRe[(4*r6  )*S+qq] = x0.x; sIm[(4*r6  )*S+qq] = x0.y; }
    if (r6 <= 31){
      sRe[(4*r6+1)*S+qq] = x2.x; sIm[(4*r6+1)*S+qq] = x2.y;
      sRe[(4*r6+2)*S+qq] = x1.x; sIm[(4*r6+2)*S+qq] = x1.y;
      sRe[(4*r6+3)*S+qq] = x3.x; sIm[(4*r6+3)*S+qq] = x3.y;
    }
  }
  __syncthreads();
  for (int idx = t; idx < NF*64; idx += 512){
    int u = idx >> 6, qq = idx & 63;
    Khat[((size_t)c*NF + u)*FN + q0 + qq] = make_float2(sRe[u*S+qq], sIm[u*S+qq]);
  }
}

// ---------------------------------------------------------------------------
// kprep_row: grid CC*4. Register-only in-place row FFTs on Khat rows
// (reads the 128 col-spectrum values, writes the full 256-bin row spectrum).
// No LDS, no barriers.
// ---------------------------------------------------------------------------
__global__ __launch_bounds__(512) void kprep_row(float2* __restrict__ Khat){
  int t = threadIdx.x, l = t & 63, w = t >> 6;
  int c = blockIdx.x >> 2, part = blockIdx.x & 3;
  Tw tw; tw_init(tw, l);
  for (int j = w; ; j += 8){
    int u = part + 4*j;
    if (u >= NF) break;
    float2* kp = Khat + ((size_t)c*NF + u)*FN;
    float2 x0 = kp[l], x1 = kp[64 + l], x2, x3;
    fft256_fwd_padded(x0, x1, x2, x3, tw, l);
    kp[l] = x0; kp[64 + l] = x1; kp[128 + l] = x2; kp[192 + l] = x3;
  }
}

// ---------------------------------------------------------------------------
// fused_conv: one block per (b,c) image. Whole 2D FFT-conv in LDS.
// Spectra: fp16 planes (stride 130, conflict-free). x and y stored exactly
// by splitting fp32 bits across the two ushort planes.
// ---------------------------------------------------------------------------
__global__ __launch_bounds__(512) void fused_conv(const float* __restrict__ x,
                                                  const float2* __restrict__ Khat,
                                                  float* __restrict__ out){
  __shared__ unsigned short hRe[131*130];
  __shared__ unsigned short hIm[131*130];
  const int S = 130;
  int t = threadIdx.x, l = t & 63, w = t >> 6;
  int blk = blockIdx.x;
  int c = blk >> 4, b = blk & 15;        // 16 consecutive blocks share c (Khat L2 reuse)
  const float* xp = x   + ((size_t)b*CC + c)*(HH*WW);
  float*       yp = out + ((size_t)b*CC + c)*(HH*WW);
  Tw tw; tw_init(tw, l);
  int r6 = __brev((unsigned)l) >> 26;

  // 1) x -> planes (exact fp32 split: hi16 in hRe, lo16 in hIm)
  for (int i = t; i < HH*WW; i += 512){
    int p = i >> 7, q = i & 127;
    unsigned int ub = __float_as_uint(xp[i]);
    hRe[p*S + q] = (unsigned short)(ub >> 16);
    hIm[p*S + q] = (unsigned short)(ub & 0xffffu);
  }
  __syncthreads();
  // 2) column forward FFTs; store bins (fp16) via cmap
  for (int qi = 0; qi < 16; ++qi){
    int q = w*16 + qi;
    unsigned int u0 = ((unsigned int)hRe[l*S+q] << 16)      | hIm[l*S+q];
    unsigned int u1 = ((unsigned int)hRe[(l+64)*S+q] << 16) | hIm[(l+64)*S+q];
    float2 x0 = make_float2(__uint_as_float(u0), 0.f);
    float2 x1 = make_float2(__uint_as_float(u1), 0.f);
    float2 x2, x3;
    fft256_fwd_padded(x0, x1, x2, x3, tw, l);
    if (r6 <= 32){ hRe[r6*S+q] = f2h(x0.x); hIm[r6*S+q] = f2h(x0.y); }
    if (r6 <= 31){
      hRe[(33+r6)*S+q] = f2h(x2.x); hIm[(33+r6)*S+q] = f2h(x2.y);
      hRe[(66+r6)*S+q] = f2h(x1.x); hIm[(66+r6)*S+q] = f2h(x1.y);
      hRe[(99+r6)*S+q] = f2h(x3.x); hIm[(99+r6)*S+q] = f2h(x3.y);
    }
  }
  __syncthreads();
  // 3) row conv: fwd -> x Khat -> inv+crop, in place (scaled 2^-10)
  for (int u = w; u < NF; u += 8){
    int pr = (u >> 2) + 33*(u & 3);
    float2 x0 = make_float2(h2f(hRe[pr*S + l]),      h2f(hIm[pr*S + l]));
    float2 x1 = make_float2(h2f(hRe[pr*S + 64 + l]), h2f(hIm[pr*S + 64 + l]));
    float2 x2, x3;
    fft256_fwd_padded(x0, x1, x2, x3, tw, l);
    const float2* kp = Khat + ((size_t)c*NF + u)*FN;
    x0 = cmul(x0, kp[l]);
    x1 = cmul(x1, kp[64 + l]);
    x2 = cmul(x2, kp[128 + l]);
    x3 = cmul(x3, kp[192 + l]);
    fft256_inv_crop(x0, x1, x2, x3, tw, l);
    hRe[pr*S + l]      = f2h(x0.x * SCL_DN); hIm[pr*S + l]      = f2h(x0.y * SCL_DN);
    hRe[pr*S + 64 + l] = f2h(x1.x * SCL_DN); hIm[pr*S + 64 + l] = f2h(x1.y * SCL_DN);
  }
  __syncthreads();
  // 4) column inverse (Hermitian gather by natural bin) + crop -> y (exact fp32 split)
  for (int qi = 0; qi < 16; ++qi){
    int q = w*16 + qi;
    float2 x0, x1, x2, x3;
    if (r6 <= 32){ x0 = make_float2(h2f(hRe[r6*S+q]),        h2f(hIm[r6*S+q])); }          // nb=4r6
    else         { x0 = make_float2(h2f(hRe[(64-r6)*S+q]),  -h2f(hIm[(64-r6)*S+q])); }     // conj(256-nb)
    if (r6 <= 31){ x1 = make_float2(h2f(hRe[(66+r6)*S+q]),   h2f(hIm[(66+r6)*S+q])); }     // nb=4r6+2
    else         { x1 = make_float2(h2f(hRe[(129-r6)*S+q]), -h2f(hIm[(129-r6)*S+q])); }
    if (r6 <= 31){ x2 = make_float2(h2f(hRe[(33+r6)*S+q]),   h2f(hIm[(33+r6)*S+q])); }     // nb=4r6+1
    else         { x2 = make_float2(h2f(hRe[(162-r6)*S+q]), -h2f(hIm[(162-r6)*S+q])); }
    if (r6 <= 31){ x3 = make_float2(h2f(hRe[(99+r6)*S+q]),   h2f(hIm[(99+r6)*S+q])); }     // nb=4r6+3
    else         { x3 = make_float2(h2f(hRe[(96-r6)*S+q]),  -h2f(hIm[(96-r6)*S+q])); }
    fft256_inv_crop(x0, x1, x2, x3, tw, l);
    unsigned int ua = __float_as_uint(x0.x * SCL_UP);
    unsigned int ub = __float_as_uint(x1.x * SCL_UP);
    hRe[l*S + q]      = (unsigned short)(ua >> 16);
    hIm[l*S + q]      = (unsigned short)(ua & 0xffffu);
    hRe[(l+64)*S + q] = (unsigned short)(ub >> 16);
    hIm[(l+64)*S + q] = (unsigned short)(ub & 0xffffu);
  }
  __syncthreads();
  // 5) out = y + x (coalesced)
  for (int i = t; i < HH*WW; i += 512){
    int p = i >> 7, q = i & 127;
    unsigned int ub = ((unsigned int)hRe[p*S + q] << 16) | hIm[p*S + q];
    yp[i] = __uint_as_float(ub) + xp[i];
  }
}

// ---------------------------------------------------------------------------
// Host launcher
// ---------------------------------------------------------------------------
extern "C" void kernel_launch(void* const* d_in, const int* in_sizes, int n_in,
                              void* d_out, int out_size, void* d_ws, size_t ws_size,
                              hipStream_t stream) {
  const float* x  = (const float*)d_in[0];
  const float* W1 = (const float*)d_in[1];
  const float* b1 = (const float*)d_in[2];
  const float* W2 = (const float*)d_in[3];
  const float* b2 = (const float*)d_in[4];
  float* out = (float*)d_out;

  float2* Khat = (float2*)d_ws;   // CC*NF*FN complex = 25.4 MB

  kprep_col<<<CC*2, 512, 0, stream>>>(W1, b1, W2, b2, Khat);
  kprep_row<<<CC*4, 512, 0, stream>>>(Khat);
  fused_conv<<<CC*BB, 512, 0, stream>>>(x, Khat, out);
}

// Round 2
// 482.814 us; speedup vs baseline: 1.4150x; 1.2002x over previous
//
#include <hip/hip_runtime.h>
#include <hip/hip_fp16.h>

#define TWO_PI 6.283185307179586f
#define PI_F   3.14159265358979f

// Problem constants
#define HH 128      // H
#define WW 128      // W
#define FN 256      // padded FFT size (2H)
#define NF 129      // FN/2+1 vertical frequency bins
#define CC 96
#define BB 16

#define SCL_DN 0.0009765625f   // 2^-10 : scale on row-conv output before fp16 store
#define SCL_UP 1024.0f

typedef unsigned int uint2v __attribute__((ext_vector_type(2)));

__device__ __forceinline__ float2 cmul(float2 a, float2 b){
  return make_float2(a.x*b.x - a.y*b.y, a.x*b.y + a.y*b.x);
}
__device__ __forceinline__ float2 cmulc(float2 a, float2 b){   // conj(a)*b
  return make_float2(a.x*b.x + a.y*b.y, a.x*b.y - a.y*b.x);
}
__device__ __forceinline__ float2 cadd(float2 a, float2 b){ return make_float2(a.x+b.x, a.y+b.y); }
__device__ __forceinline__ float2 csub(float2 a, float2 b){ return make_float2(a.x-b.x, a.y-b.y); }
__device__ __forceinline__ float2 shflx(float2 v, int m){
  float2 r; r.x = __shfl_xor(v.x, m, 64); r.y = __shfl_xor(v.y, m, 64); return r;
}
__device__ __forceinline__ unsigned short f2h(float v){ return __half_as_ushort(__float2half(v)); }
__device__ __forceinline__ float h2f(unsigned short u){ return __half2float(__ushort_as_half(u)); }

// ---------------------------------------------------------------------------
// Cross-lane exchange helpers that stay on the VALU pipe (gfx950):
//   swp32/swp16: one v_permlane{32,16}_swap_b32 per 32b yields BOTH the
//   low-half value (lane l&~h) and high-half value (lane l|h) on every lane.
//   dppx<CTRL>: quad_perm DPP for xor-1 / xor-2.
// Only h=8 and h=4 stages remain ds_swizzle (LDS pipe) — deliberate, to
// co-schedule with the (now dominant) VALU work.
// ---------------------------------------------------------------------------
__device__ __forceinline__ void swp32(float2 v, float2& lo, float2& hi){
  uint2v rx = __builtin_amdgcn_permlane32_swap(__float_as_uint(v.x), __float_as_uint(v.x), false, false);
  uint2v ry = __builtin_amdgcn_permlane32_swap(__float_as_uint(v.y), __float_as_uint(v.y), false, false);
  lo = make_float2(__uint_as_float(rx[0]), __uint_as_float(ry[0]));
  hi = make_float2(__uint_as_float(rx[1]), __uint_as_float(ry[1]));
}
__device__ __forceinline__ void swp16(float2 v, float2& lo, float2& hi){
  uint2v rx = __builtin_amdgcn_permlane16_swap(__float_as_uint(v.x), __float_as_uint(v.x), false, false);
  uint2v ry = __builtin_amdgcn_permlane16_swap(__float_as_uint(v.y), __float_as_uint(v.y), false, false);
  lo = make_float2(__uint_as_float(rx[0]), __uint_as_float(ry[0]));
  hi = make_float2(__uint_as_float(rx[1]), __uint_as_float(ry[1]));
}
template<int CTRL>
__device__ __forceinline__ float2 dppx(float2 v){
  float2 r;
  r.x = __uint_as_float((unsigned)__builtin_amdgcn_update_dpp(0, (int)__float_as_uint(v.x), CTRL, 0xF, 0xF, true));
  r.y = __uint_as_float((unsigned)__builtin_amdgcn_update_dpp(0, (int)__float_as_uint(v.y), CTRL, 0xF, 0xF, true));
  return r;
}
#define DPP_XOR1 0xB1   // quad_perm [1,0,3,2]
#define DPP_XOR2 0x4E   // quad_perm [2,3,0,1]

// ---------------------------------------------------------------------------
// Wave-resident 256-pt FFT. Lane l holds positions l, l+64, l+128, l+192.
// Forward = DIF (natural in -> bit-reversed positions out). Inverse = DIT.
//
// Select-free butterflies: every DIF exchange is
//     s = other + sigma*own          (sigma = +1 up-lane / -1 down-lane)
//     x = cmul(wf, s)                (wf = (1,0) up-lane / w down-lane)
// with sigma and wf PRECOMPUTED PER LANE in tw_init. 6 VALU ops/exchange
// instead of 10-14 (no dual-path + cndmask).
// ---------------------------------------------------------------------------
struct Tw {
  float2 w128a, w128b, w64;
  float2 wc[5];   // raw stage twiddles, h = 32,16,8,4,2 (angle dep. on l&(h-1))
  float2 wf[5];   // forward per-lane post-multiplier: (l&h)? wc : (1,0)
  float  sg[5];   // (l&h) ? -1 : +1
  float  sg1;     // (l&1) ? -1 : +1
};

__device__ __forceinline__ void tw_init(Tw& t, int l){
  float s, c;
  sincosf(-TWO_PI * (float)l * (1.0f/256.0f), &s, &c);
  t.w128a = make_float2(c, s);                 // W256^l
  t.w128b = make_float2(s, -c);                // W256^(l+64)
  t.w64   = make_float2(c*c - s*s, 2.0f*c*s);  // W256^(2l)
  const int hs[5] = {32,16,8,4,2};
#pragma unroll
  for (int i = 0; i < 5; ++i){
    int h = hs[i];
    float ang = -PI_F * (float)(l & (h-1)) / (float)h;
    sincosf(ang, &s, &c);
    t.wc[i] = make_float2(c, s);
    bool dn = (l & h) != 0;
    t.wf[i] = dn ? t.wc[i] : make_float2(1.0f, 0.0f);
    t.sg[i] = dn ? -1.0f : 1.0f;
  }
  t.sg1 = (l & 1) ? -1.0f : 1.0f;
}

// forward exchange, partner-value form (ds_swizzle / DPP stages)
#define FX_OTHER(X, OTHER, SG, WF) { \
  float2 o_ = OTHER; float2 s_; \
  s_.x = fmaf(SG, X.x, o_.x); s_.y = fmaf(SG, X.y, o_.y); \
  X = cmul(WF, s_); }
// forward exchange, both-halves form (permlane stages)
#define FX_LOHI(X, SWPF, SG, WF) { \
  float2 lo_, hi_, s_; SWPF(X, lo_, hi_); \
  s_.x = fmaf(SG, hi_.x, lo_.x); s_.y = fmaf(SG, hi_.y, lo_.y); \
  X = cmul(WF, s_); }
// inverse exchange, both-halves form:  x = lo + sg * (conj(w) * hi)
#define IX_LOHI(X, SWPF, SG, WC) { \
  float2 lo_, hi_, m_; SWPF(X, lo_, hi_); \
  m_ = cmulc(WC, hi_); \
  X.x = fmaf(SG, m_.x, lo_.x); X.y = fmaf(SG, m_.y, lo_.y); }
// inverse exchange, partner form (needs role swap):
//   up: x + conj(w)*o   dn: o - conj(w)*x
#define IX_OTHER(X, OTHER, UP, SG, WC) { \
  float2 o_ = OTHER; \
  float2 A_ = UP ? X : o_; \
  float2 B_ = UP ? o_ : X; \
  float2 m_ = cmulc(WC, B_); \
  X.x = fmaf(SG, m_.x, A_.x); X.y = fmaf(SG, m_.y, A_.y); }

__device__ __forceinline__ void fft256_fwd_padded(float2& x0, float2& x1,
                                                  float2& x2, float2& x3,
                                                  const Tw& t, int l){
  x2 = cmul(x0, t.w128a);
  x3 = cmul(x1, t.w128b);
  float2 a = x0, b = x1;
  x0 = cadd(a, b); x1 = cmul(csub(a, b), t.w64);
  a = x2; b = x3;
  x2 = cadd(a, b); x3 = cmul(csub(a, b), t.w64);
  // h = 32 : permlane32_swap (VALU)
  FX_LOHI(x0, swp32, t.sg[0], t.wf[0]);
  FX_LOHI(x1, swp32, t.sg[0], t.wf[0]);
  FX_LOHI(x2, swp32, t.sg[0], t.wf[0]);
  FX_LOHI(x3, swp32, t.sg[0], t.wf[0]);
  // h = 16 : permlane16_swap (VALU)
  FX_LOHI(x0, swp16, t.sg[1], t.wf[1]);
  FX_LOHI(x1, swp16, t.sg[1], t.wf[1]);
  FX_LOHI(x2, swp16, t.sg[1], t.wf[1]);
  FX_LOHI(x3, swp16, t.sg[1], t.wf[1]);
  // h = 8, 4 : ds_swizzle
  FX_OTHER(x0, shflx(x0, 8), t.sg[2], t.wf[2]);
  FX_OTHER(x1, shflx(x1, 8), t.sg[2], t.wf[2]);
  FX_OTHER(x2, shflx(x2, 8), t.sg[2], t.wf[2]);
  FX_OTHER(x3, shflx(x3, 8), t.sg[2], t.wf[2]);
  FX_OTHER(x0, shflx(x0, 4), t.sg[3], t.wf[3]);
  FX_OTHER(x1, shflx(x1, 4), t.sg[3], t.wf[3]);
  FX_OTHER(x2, shflx(x2, 4), t.sg[3], t.wf[3]);
  FX_OTHER(x3, shflx(x3, 4), t.sg[3], t.wf[3]);
  // h = 2 : DPP quad_perm (VALU)
  FX_OTHER(x0, dppx<DPP_XOR2>(x0), t.sg[4], t.wf[4]);
  FX_OTHER(x1, dppx<DPP_XOR2>(x1), t.sg[4], t.wf[4]);
  FX_OTHER(x2, dppx<DPP_XOR2>(x2), t.sg[4], t.wf[4]);
  FX_OTHER(x3, dppx<DPP_XOR2>(x3), t.sg[4], t.wf[4]);
  // h = 1 : DPP quad_perm, no twiddle:  x = other + sg1*own
  {
    float2 o;
    o = dppx<DPP_XOR1>(x0); x0.x = fmaf(t.sg1, x0.x, o.x); x0.y = fmaf(t.sg1, x0.y, o.y);
    o = dppx<DPP_XOR1>(x1); x1.x = fmaf(t.sg1, x1.x, o.x); x1.y = fmaf(t.sg1, x1.y, o.y);
    o = dppx<DPP_XOR1>(x2); x2.x = fmaf(t.sg1, x2.x, o.x); x2.y = fmaf(t.sg1, x2.y, o.y);
    o = dppx<DPP_XOR1>(x3); x3.x = fmaf(t.sg1, x3.x, o.x); x3.y = fmaf(t.sg1, x3.y, o.y);
  }
}

__device__ __forceinline__ void fft256_inv_crop(float2& x0, float2& x1,
                                                float2& x2, float2& x3,
                                                const Tw& t, int l){
  // h = 1 : DPP, no twiddle
  {
    float2 o;
    o = dppx<DPP_XOR1>(x0); x0.x = fmaf(t.sg1, x0.x, o.x); x0.y = fmaf(t.sg1, x0.y, o.y);
    o = dppx<DPP_XOR1>(x1); x1.x = fmaf(t.sg1, x1.x, o.x); x1.y = fmaf(t.sg1, x1.y, o.y);
    o = dppx<DPP_XOR1>(x2); x2.x = fmaf(t.sg1, x2.x, o.x); x2.y = fmaf(t.sg1, x2.y, o.y);
    o = dppx<DPP_XOR1>(x3); x3.x = fmaf(t.sg1, x3.x, o.x); x3.y = fmaf(t.sg1, x3.y, o.y);
  }
  // h = 2 : DPP
  {
    bool up = (l & 2) == 0;
    IX_OTHER(x0, dppx<DPP_XOR2>(x0), up, t.sg[4], t.wc[4]);
    IX_OTHER(x1, dppx<DPP_XOR2>(x1), up, t.sg[4], t.wc[4]);
    IX_OTHER(x2, dppx<DPP_XOR2>(x2), up, t.sg[4], t.wc[4]);
    IX_OTHER(x3, dppx<DPP_XOR2>(x3), up, t.sg[4], t.wc[4]);
  }
  // h = 4, 8 : ds_swizzle
  {
    bool up = (l & 4) == 0;
    IX_OTHER(x0, shflx(x0, 4), up, t.sg[3], t.wc[3]);
    IX_OTHER(x1, shflx(x1, 4), up, t.sg[3], t.wc[3]);
    IX_OTHER(x2, shflx(x2, 4), up, t.sg[3], t.wc[3]);
    IX_OTHER(x3, shflx(x3, 4), up, t.sg[3], t.wc[3]);
  }
  {
    bool up = (l & 8) == 0;
    IX_OTHER(x0, shflx(x0, 8), up, t.sg[2], t.wc[2]);
    IX_OTHER(x1, shflx(x1, 8), up, t.sg[2], t.wc[2]);
    IX_OTHER(x2, shflx(x2, 8), up, t.sg[2], t.wc[2]);
    IX_OTHER(x3, shflx(x3, 8), up, t.sg[2], t.wc[2]);
  }
  // h = 16 : permlane16_swap
  IX_LOHI(x0, swp16, t.sg[1], t.wc[1]);
  IX_LOHI(x1, swp16, t.sg[1], t.wc[1]);
  IX_LOHI(x2, swp16, t.sg[1], t.wc[1]);
  IX_LOHI(x3, swp16, t.sg[1], t.wc[1]);
  // h = 32 : permlane32_swap
  IX_LOHI(x0, swp32, t.sg[0], t.wc[0]);
  IX_LOHI(x1, swp32, t.sg[0], t.wc[0]);
  IX_LOHI(x2, swp32, t.sg[0], t.wc[0]);
  IX_LOHI(x3, swp32, t.sg[0], t.wc[0]);
  {
    float2 w = make_float2(t.w64.x, -t.w64.y);
    float2 t0 = cmul(w, x1); x1 = csub(x0, t0); x0 = cadd(x0, t0);
    float2 t1 = cmul(w, x3); x3 = csub(x2, t1); x2 = cadd(x2, t1);
  }
  {
    float2 wa = make_float2(t.w128a.x, -t.w128a.y);
    float2 wb = make_float2(t.w128b.x, -t.w128b.y);
    x0 = cadd(x0, cmul(wa, x2));
    x1 = cadd(x1, cmul(wb, x3));
  }
}

// ---------------------------------------------------------------------------
// kprep_col: grid CC*2. Block handles 64 columns of channel c. MLP computed
// inline per lane (no staging), column forward FFT, natural-bin spectrum to
// LDS, coalesced write into the FRONT HALF (v=0..127) of Khat rows.
// ---------------------------------------------------------------------------
__global__ __launch_bounds__(512) void kprep_col(const float* __restrict__ W1,
                                                 const float* __restrict__ b1,
                                                 const float* __restrict__ W2,
                                                 const float* __restrict__ b2,
                                                 float2* __restrict__ Khat){
  __shared__ float sRe[NF*65];
  __shared__ float sIm[NF*65];
  const int S = 65;
  int t = threadIdx.x, l = t & 63, w = t >> 6;
  int c  = blockIdx.x >> 1;
  int q0 = (blockIdx.x & 1) * 64;
  Tw tw; tw_init(tw, l);
  int r6 = __brev((unsigned)l) >> 26;

  float w1y[16], w1x[16], bb1[16], w2r[16];
#pragma unroll
  for (int h = 0; h < 16; ++h){
    w1y[h] = W1[h]; w1x[h] = W1[16+h]; bb1[h] = b1[h]; w2r[h] = W2[h*CC + c];
  }
  float bb2 = b2[c];
  float gy0 = (float)l        * (1.0f/127.0f);
  float gy1 = (float)(l + 64) * (1.0f/127.0f);

  for (int qi = 0; qi < 8; ++qi){
    int qq = w*8 + qi;                       // 0..63
    float gx = (float)(q0 + qq) * (1.0f/127.0f);
    float a0 = bb2, a1 = bb2;
#pragma unroll
    for (int h = 0; h < 16; ++h){
      float hx = gx*w1x[h] + bb1[h];
      a0 += fmaxf(gy0*w1y[h] + hx, 0.0f) * w2r[h];
      a1 += fmaxf(gy1*w1y[h] + hx, 0.0f) * w2r[h];
    }
    float2 x0 = make_float2(a0, 0.f);
    float2 x1 = make_float2(a1, 0.f);
    float2 x2, x3;
    fft256_fwd_padded(x0, x1, x2, x3, tw, l);
    if (r6 <= 32){ sRe[(4*r6  )*S+qq] = x0.x; sIm[(4*r6  )*S+qq] = x0.y; }
    if (r6 <= 31){
      sRe[(4*r6+1)*S+qq] = x2.x; sIm[(4*r6+1)*S+qq] = x2.y;
      sRe[(4*r6+2)*S+qq] = x1.x; sIm[(4*r6+2)*S+qq] = x1.y;
      sRe[(4*r6+3)*S+qq] = x3.x; sIm[(4*r6+3)*S+qq] = x3.y;
    }
  }
  __syncthreads();
  for (int idx = t; idx < NF*64; idx += 512){
    int u = idx >> 6, qq = idx & 63;
    Khat[((size_t)c*NF + u)*FN + q0 + qq] = make_float2(sRe[u*S+qq], sIm[u*S+qq]);
  }
}

// ---------------------------------------------------------------------------
// kprep_row: grid CC*4. Register-only in-place row FFTs on Khat rows
// (reads the 128 col-spectrum values, writes the full 256-bin row spectrum).
// No LDS, no barriers.
// ---------------------------------------------------------------------------
__global__ __launch_bounds__(512) void kprep_row(float2* __restrict__ Khat){
  int t = threadIdx.x, l = t & 63, w = t >> 6;
  int c = blockIdx.x >> 2, part = blockIdx.x & 3;
  Tw tw; tw_init(tw, l);
  for (int j = w; ; j += 8){
    int u = part + 4*j;
    if (u >= NF) break;
    float2* kp = Khat + ((size_t)c*NF + u)*FN;
    float2 x0 = kp[l], x1 = kp[64 + l], x2, x3;
    fft256_fwd_padded(x0, x1, x2, x3, tw, l);
    kp[l] = x0; kp[64 + l] = x1; kp[128 + l] = x2; kp[192 + l] = x3;
  }
}

// ---------------------------------------------------------------------------
// fused_conv: one block per (b,c) image. Whole 2D FFT-conv in LDS.
// Spectra: fp16 planes (stride 130, conflict-free). x and y stored exactly
// by splitting fp32 bits across the two ushort planes.
// ---------------------------------------------------------------------------
__global__ __launch_bounds__(512) void fused_conv(const float* __restrict__ x,
                                                  const float2* __restrict__ Khat,
                                                  float* __restrict__ out){
  __shared__ unsigned short hRe[131*130];
  __shared__ unsigned short hIm[131*130];
  const int S = 130;
  int t = threadIdx.x, l = t & 63, w = t >> 6;
  int blk = blockIdx.x;
  int c = blk >> 4, b = blk & 15;        // 16 consecutive blocks share c (Khat L2 reuse)
  const float* xp = x   + ((size_t)b*CC + c)*(HH*WW);
  float*       yp = out + ((size_t)b*CC + c)*(HH*WW);
  Tw tw; tw_init(tw, l);
  int r6 = __brev((unsigned)l) >> 26;

  // 1) x -> planes (exact fp32 split: hi16 in hRe, lo16 in hIm)
  for (int i = t; i < HH*WW; i += 512){
    int p = i >> 7, q = i & 127;
    unsigned int ub = __float_as_uint(xp[i]);
    hRe[p*S + q] = (unsigned short)(ub >> 16);
    hIm[p*S + q] = (unsigned short)(ub & 0xffffu);
  }
  __syncthreads();
  // 2) column forward FFTs; store bins (fp16) via cmap
  for (int qi = 0; qi < 16; ++qi){
    int q = w*16 + qi;
    unsigned int u0 = ((unsigned int)hRe[l*S+q] << 16)      | hIm[l*S+q];
    unsigned int u1 = ((unsigned int)hRe[(l+64)*S+q] << 16) | hIm[(l+64)*S+q];
    float2 x0 = make_float2(__uint_as_float(u0), 0.f);
    float2 x1 = make_float2(__uint_as_float(u1), 0.f);
    float2 x2, x3;
    fft256_fwd_padded(x0, x1, x2, x3, tw, l);
    if (r6 <= 32){ hRe[r6*S+q] = f2h(x0.x); hIm[r6*S+q] = f2h(x0.y); }
    if (r6 <= 31){
      hRe[(33+r6)*S+q] = f2h(x2.x); hIm[(33+r6)*S+q] = f2h(x2.y);
      hRe[(66+r6)*S+q] = f2h(x1.x); hIm[(66+r6)*S+q] = f2h(x1.y);
      hRe[(99+r6)*S+q] = f2h(x3.x); hIm[(99+r6)*S+q] = f2h(x3.y);
    }
  }
  __syncthreads();
  // 3) row conv: fwd -> x Khat -> inv+crop, in place (scaled 2^-10)
  for (int u = w; u < NF; u += 8){
    int pr = (u >> 2) + 33*(u & 3);
    float2 x0 = make_float2(h2f(hRe[pr*S + l]),      h2f(hIm[pr*S + l]));
    float2 x1 = make_float2(h2f(hRe[pr*S + 64 + l]), h2f(hIm[pr*S + 64 + l]));
    float2 x2, x3;
    fft256_fwd_padded(x0, x1, x2, x3, tw, l);
    const float2* kp = Khat + ((size_t)c*NF + u)*FN;
    x0 = cmul(x0, kp[l]);
    x1 = cmul(x1, kp[64 + l]);
    x2 = cmul(x2, kp[128 + l]);
    x3 = cmul(x3, kp[192 + l]);
    fft256_inv_crop(x0, x1, x2, x3, tw, l);
    hRe[pr*S + l]      = f2h(x0.x * SCL_DN); hIm[pr*S + l]      = f2h(x0.y * SCL_DN);
    hRe[pr*S + 64 + l] = f2h(x1.x * SCL_DN); hIm[pr*S + 64 + l] = f2h(x1.y * SCL_DN);
  }
  __syncthreads();
  // 4) column inverse (Hermitian gather by natural bin) + crop -> y (exact fp32 split)
  for (int qi = 0; qi < 16; ++qi){
    int q = w*16 + qi;
    float2 x0, x1, x2, x3;
    if (r6 <= 32){ x0 = make_float2(h2f(hRe[r6*S+q]),        h2f(hIm[r6*S+q])); }          // nb=4r6
    else         { x0 = make_float2(h2f(hRe[(64-r6)*S+q]),  -h2f(hIm[(64-r6)*S+q])); }     // conj(256-nb)
    if (r6 <= 31){ x1 = make_float2(h2f(hRe[(66+r6)*S+q]),   h2f(hIm[(66+r6)*S+q])); }     // nb=4r6+2
    else         { x1 = make_float2(h2f(hRe[(129-r6)*S+q]), -h2f(hIm[(129-r6)*S+q])); }
    if (r6 <= 31){ x2 = make_float2(h2f(hRe[(33+r6)*S+q]),   h2f(hIm[(33+r6)*S+q])); }     // nb=4r6+1
    else         { x2 = make_float2(h2f(hRe[(162-r6)*S+q]), -h2f(hIm[(162-r6)*S+q])); }
    if (r6 <= 31){ x3 = make_float2(h2f(hRe[(99+r6)*S+q]),   h2f(hIm[(99+r6)*S+q])); }     // nb=4r6+3
    else         { x3 = make_float2(h2f(hRe[(96-r6)*S+q]),  -h2f(hIm[(96-r6)*S+q])); }
    fft256_inv_crop(x0, x1, x2, x3, tw, l);
    unsigned int ua = __float_as_uint(x0.x * SCL_UP);
    unsigned int ub = __float_as_uint(x1.x * SCL_UP);
    hRe[l*S + q]      = (unsigned short)(ua >> 16);
    hIm[l*S + q]      = (unsigned short)(ua & 0xffffu);
    hRe[(l+64)*S + q] = (unsigned short)(ub >> 16);
    hIm[(l+64)*S + q] = (unsigned short)(ub & 0xffffu);
  }
  __syncthreads();
  // 5) out = y + x (coalesced)
  for (int i = t; i < HH*WW; i += 512){
    int p = i >> 7, q = i & 127;
    unsigned int ub = ((unsigned int)hRe[p*S + q] << 16) | hIm[p*S + q];
    yp[i] = __uint_as_float(ub) + xp[i];
  }
}

// ---------------------------------------------------------------------------
// Host launcher
// ---------------------------------------------------------------------------
extern "C" void kernel_launch(void* const* d_in, const int* in_sizes, int n_in,
                              void* d_out, int out_size, void* d_ws, size_t ws_size,
                              hipStream_t stream) {
  const float* x  = (const float*)d_in[0];
  const float* W1 = (const float*)d_in[1];
  const float* b1 = (const float*)d_in[2];
  const float* W2 = (const float*)d_in[3];
  const float* b2 = (const float*)d_in[4];
  float* out = (float*)d_out;

  float2* Khat = (float2*)d_ws;   // CC*NF*FN complex = 25.4 MB

  kprep_col<<<CC*2, 512, 0, stream>>>(W1, b1, W2, b2, Khat);
  kprep_row<<<CC*4, 512, 0, stream>>>(Khat);
  fused_conv<<<CC*BB, 512, 0, stream>>>(x, Khat, out);
}

// Round 3
// 425.100 us; speedup vs baseline: 1.6071x; 1.1358x over previous
//
#include <hip/hip_runtime.h>
#include <hip/hip_fp16.h>

#define TWO_PI 6.283185307179586f
#define PI_F   3.14159265358979f

// Problem constants
#define HH 128      // H
#define WW 128      // W
#define FN 256      // padded FFT size (2H)
#define NF 129      // FN/2+1 vertical frequency bins
#define CC 96
#define BB 16

#define SCL_DN 0.0009765625f   // 2^-10 : scale on row-conv output before fp16 store
#define SCL_UP 1024.0f

typedef unsigned int uint2v __attribute__((ext_vector_type(2)));

__device__ __forceinline__ float2 cmul(float2 a, float2 b){
  return make_float2(a.x*b.x - a.y*b.y, a.x*b.y + a.y*b.x);
}
__device__ __forceinline__ float2 cmulc(float2 a, float2 b){   // conj(a)*b
  return make_float2(a.x*b.x + a.y*b.y, a.x*b.y - a.y*b.x);
}
__device__ __forceinline__ float2 cadd(float2 a, float2 b){ return make_float2(a.x+b.x, a.y+b.y); }
__device__ __forceinline__ float2 csub(float2 a, float2 b){ return make_float2(a.x-b.x, a.y-b.y); }
__device__ __forceinline__ float2 shflx(float2 v, int m){
  float2 r; r.x = __shfl_xor(v.x, m, 64); r.y = __shfl_xor(v.y, m, 64); return r;
}
__device__ __forceinline__ float2 shfli(float2 v, int idx){
  float2 r; r.x = __shfl(v.x, idx, 64); r.y = __shfl(v.y, idx, 64); return r;
}
__device__ __forceinline__ unsigned short f2h(float v){ return __half_as_ushort(__float2half(v)); }
__device__ __forceinline__ float h2f(unsigned short u){ return __half2float(__ushort_as_half(u)); }

// ---------------------------------------------------------------------------
// Cross-lane exchange helpers on the VALU pipe (gfx950): permlane32/16 swaps
// give both halves; DPP quad_perm for xor-1/xor-2. h=8/h=4 stay ds_swizzle.
// ---------------------------------------------------------------------------
__device__ __forceinline__ void swp32(float2 v, float2& lo, float2& hi){
  uint2v rx = __builtin_amdgcn_permlane32_swap(__float_as_uint(v.x), __float_as_uint(v.x), false, false);
  uint2v ry = __builtin_amdgcn_permlane32_swap(__float_as_uint(v.y), __float_as_uint(v.y), false, false);
  lo = make_float2(__uint_as_float(rx[0]), __uint_as_float(ry[0]));
  hi = make_float2(__uint_as_float(rx[1]), __uint_as_float(ry[1]));
}
__device__ __forceinline__ void swp16(float2 v, float2& lo, float2& hi){
  uint2v rx = __builtin_amdgcn_permlane16_swap(__float_as_uint(v.x), __float_as_uint(v.x), false, false);
  uint2v ry = __builtin_amdgcn_permlane16_swap(__float_as_uint(v.y), __float_as_uint(v.y), false, false);
  lo = make_float2(__uint_as_float(rx[0]), __uint_as_float(ry[0]));
  hi = make_float2(__uint_as_float(rx[1]), __uint_as_float(ry[1]));
}
template<int CTRL>
__device__ __forceinline__ float2 dppx(float2 v){
  float2 r;
  r.x = __uint_as_float((unsigned)__builtin_amdgcn_update_dpp(0, (int)__float_as_uint(v.x), CTRL, 0xF, 0xF, true));
  r.y = __uint_as_float((unsigned)__builtin_amdgcn_update_dpp(0, (int)__float_as_uint(v.y), CTRL, 0xF, 0xF, true));
  return r;
}
#define DPP_XOR1 0xB1   // quad_perm [1,0,3,2]
#define DPP_XOR2 0x4E   // quad_perm [2,3,0,1]

// ---------------------------------------------------------------------------
// Wave-resident 256-pt FFT. Lane l holds positions l, l+64, l+128, l+192.
// Forward DIF output: lane l holds natural bins 4*br6(l)+{0,1,2,3} in regs
// (x0, x2, x1, x3) respectively. Select-free butterflies with per-lane
// precomputed sigma / twiddle (Tw).
// ---------------------------------------------------------------------------
struct Tw {
  float2 w128a, w128b, w64;
  float2 wc[5];   // raw stage twiddles, h = 32,16,8,4,2
  float2 wf[5];   // forward per-lane post-multiplier: (l&h)? wc : (1,0)
  float  sg[5];   // (l&h) ? -1 : +1
  float  sg1;     // (l&1) ? -1 : +1
};

__device__ __forceinline__ void tw_init(Tw& t, int l){
  float s, c;
  sincosf(-TWO_PI * (float)l * (1.0f/256.0f), &s, &c);
  t.w128a = make_float2(c, s);                 // W256^l
  t.w128b = make_float2(s, -c);                // W256^(l+64)
  t.w64   = make_float2(c*c - s*s, 2.0f*c*s);  // W256^(2l)
  const int hs[5] = {32,16,8,4,2};
#pragma unroll
  for (int i = 0; i < 5; ++i){
    int h = hs[i];
    float ang = -PI_F * (float)(l & (h-1)) / (float)h;
    sincosf(ang, &s, &c);
    t.wc[i] = make_float2(c, s);
    bool dn = (l & h) != 0;
    t.wf[i] = dn ? t.wc[i] : make_float2(1.0f, 0.0f);
    t.sg[i] = dn ? -1.0f : 1.0f;
  }
  t.sg1 = (l & 1) ? -1.0f : 1.0f;
}

// forward exchange, partner-value form (ds_swizzle / DPP stages)
#define FX_OTHER(X, OTHER, SG, WF) { \
  float2 o_ = OTHER; float2 s_; \
  s_.x = fmaf(SG, X.x, o_.x); s_.y = fmaf(SG, X.y, o_.y); \
  X = cmul(WF, s_); }
// forward exchange, both-halves form (permlane stages)
#define FX_LOHI(X, SWPF, SG, WF) { \
  float2 lo_, hi_, s_; SWPF(X, lo_, hi_); \
  s_.x = fmaf(SG, hi_.x, lo_.x); s_.y = fmaf(SG, hi_.y, lo_.y); \
  X = cmul(WF, s_); }
// inverse exchange, both-halves form:  x = lo + sg * (conj(w) * hi)
#define IX_LOHI(X, SWPF, SG, WC) { \
  float2 lo_, hi_, m_; SWPF(X, lo_, hi_); \
  m_ = cmulc(WC, hi_); \
  X.x = fmaf(SG, m_.x, lo_.x); X.y = fmaf(SG, m_.y, lo_.y); }
// inverse exchange, partner form (needs role swap)
#define IX_OTHER(X, OTHER, UP, SG, WC) { \
  float2 o_ = OTHER; \
  float2 A_ = UP ? X : o_; \
  float2 B_ = UP ? o_ : X; \
  float2 m_ = cmulc(WC, B_); \
  X.x = fmaf(SG, m_.x, A_.x); X.y = fmaf(SG, m_.y, A_.y); }

__device__ __forceinline__ void fft256_fwd_padded(float2& x0, float2& x1,
                                                  float2& x2, float2& x3,
                                                  const Tw& t, int l){
  x2 = cmul(x0, t.w128a);
  x3 = cmul(x1, t.w128b);
  float2 a = x0, b = x1;
  x0 = cadd(a, b); x1 = cmul(csub(a, b), t.w64);
  a = x2; b = x3;
  x2 = cadd(a, b); x3 = cmul(csub(a, b), t.w64);
  // h = 32 : permlane32_swap (VALU)
  FX_LOHI(x0, swp32, t.sg[0], t.wf[0]);
  FX_LOHI(x1, swp32, t.sg[0], t.wf[0]);
  FX_LOHI(x2, swp32, t.sg[0], t.wf[0]);
  FX_LOHI(x3, swp32, t.sg[0], t.wf[0]);
  // h = 16 : permlane16_swap (VALU)
  FX_LOHI(x0, swp16, t.sg[1], t.wf[1]);
  FX_LOHI(x1, swp16, t.sg[1], t.wf[1]);
  FX_LOHI(x2, swp16, t.sg[1], t.wf[1]);
  FX_LOHI(x3, swp16, t.sg[1], t.wf[1]);
  // h = 8, 4 : ds_swizzle
  FX_OTHER(x0, shflx(x0, 8), t.sg[2], t.wf[2]);
  FX_OTHER(x1, shflx(x1, 8), t.sg[2], t.wf[2]);
  FX_OTHER(x2, shflx(x2, 8), t.sg[2], t.wf[2]);
  FX_OTHER(x3, shflx(x3, 8), t.sg[2], t.wf[2]);
  FX_OTHER(x0, shflx(x0, 4), t.sg[3], t.wf[3]);
  FX_OTHER(x1, shflx(x1, 4), t.sg[3], t.wf[3]);
  FX_OTHER(x2, shflx(x2, 4), t.sg[3], t.wf[3]);
  FX_OTHER(x3, shflx(x3, 4), t.sg[3], t.wf[3]);
  // h = 2 : DPP quad_perm (VALU)
  FX_OTHER(x0, dppx<DPP_XOR2>(x0), t.sg[4], t.wf[4]);
  FX_OTHER(x1, dppx<DPP_XOR2>(x1), t.sg[4], t.wf[4]);
  FX_OTHER(x2, dppx<DPP_XOR2>(x2), t.sg[4], t.wf[4]);
  FX_OTHER(x3, dppx<DPP_XOR2>(x3), t.sg[4], t.wf[4]);
  // h = 1 : DPP quad_perm, no twiddle
  {
    float2 o;
    o = dppx<DPP_XOR1>(x0); x0.x = fmaf(t.sg1, x0.x, o.x); x0.y = fmaf(t.sg1, x0.y, o.y);
    o = dppx<DPP_XOR1>(x1); x1.x = fmaf(t.sg1, x1.x, o.x); x1.y = fmaf(t.sg1, x1.y, o.y);
    o = dppx<DPP_XOR1>(x2); x2.x = fmaf(t.sg1, x2.x, o.x); x2.y = fmaf(t.sg1, x2.y, o.y);
    o = dppx<DPP_XOR1>(x3); x3.x = fmaf(t.sg1, x3.x, o.x); x3.y = fmaf(t.sg1, x3.y, o.y);
  }
}

__device__ __forceinline__ void fft256_inv_crop(float2& x0, float2& x1,
                                                float2& x2, float2& x3,
                                                const Tw& t, int l){
  // h = 1 : DPP, no twiddle
  {
    float2 o;
    o = dppx<DPP_XOR1>(x0); x0.x = fmaf(t.sg1, x0.x, o.x); x0.y = fmaf(t.sg1, x0.y, o.y);
    o = dppx<DPP_XOR1>(x1); x1.x = fmaf(t.sg1, x1.x, o.x); x1.y = fmaf(t.sg1, x1.y, o.y);
    o = dppx<DPP_XOR1>(x2); x2.x = fmaf(t.sg1, x2.x, o.x); x2.y = fmaf(t.sg1, x2.y, o.y);
    o = dppx<DPP_XOR1>(x3); x3.x = fmaf(t.sg1, x3.x, o.x); x3.y = fmaf(t.sg1, x3.y, o.y);
  }
  // h = 2 : DPP
  {
    bool up = (l & 2) == 0;
    IX_OTHER(x0, dppx<DPP_XOR2>(x0), up, t.sg[4], t.wc[4]);
    IX_OTHER(x1, dppx<DPP_XOR2>(x1), up, t.sg[4], t.wc[4]);
    IX_OTHER(x2, dppx<DPP_XOR2>(x2), up, t.sg[4], t.wc[4]);
    IX_OTHER(x3, dppx<DPP_XOR2>(x3), up, t.sg[4], t.wc[4]);
  }
  // h = 4, 8 : ds_swizzle
  {
    bool up = (l & 4) == 0;
    IX_OTHER(x0, shflx(x0, 4), up, t.sg[3], t.wc[3]);
    IX_OTHER(x1, shflx(x1, 4), up, t.sg[3], t.wc[3]);
    IX_OTHER(x2, shflx(x2, 4), up, t.sg[3], t.wc[3]);
    IX_OTHER(x3, shflx(x3, 4), up, t.sg[3], t.wc[3]);
  }
  {
    bool up = (l & 8) == 0;
    IX_OTHER(x0, shflx(x0, 8), up, t.sg[2], t.wc[2]);
    IX_OTHER(x1, shflx(x1, 8), up, t.sg[2], t.wc[2]);
    IX_OTHER(x2, shflx(x2, 8), up, t.sg[2], t.wc[2]);
    IX_OTHER(x3, shflx(x3, 8), up, t.sg[2], t.wc[2]);
  }
  // h = 16 : permlane16_swap
  IX_LOHI(x0, swp16, t.sg[1], t.wc[1]);
  IX_LOHI(x1, swp16, t.sg[1], t.wc[1]);
  IX_LOHI(x2, swp16, t.sg[1], t.wc[1]);
  IX_LOHI(x3, swp16, t.sg[1], t.wc[1]);
  // h = 32 : permlane32_swap
  IX_LOHI(x0, swp32, t.sg[0], t.wc[0]);
  IX_LOHI(x1, swp32, t.sg[0], t.wc[0]);
  IX_LOHI(x2, swp32, t.sg[0], t.wc[0]);
  IX_LOHI(x3, swp32, t.sg[0], t.wc[0]);
  {
    float2 w = make_float2(t.w64.x, -t.w64.y);
    float2 t0 = cmul(w, x1); x1 = csub(x0, t0); x0 = cadd(x0, t0);
    float2 t1 = cmul(w, x3); x3 = csub(x2, t1); x2 = cadd(x2, t1);
  }
  {
    float2 wa = make_float2(t.w128a.x, -t.w128a.y);
    float2 wb = make_float2(t.w128b.x, -t.w128b.y);
    x0 = cadd(x0, cmul(wa, x2));
    x1 = cadd(x1, cmul(wb, x3));
  }
}

// ---------------------------------------------------------------------------
// Two-real-FFTs-in-one-complex packing.
// Lane l's bins U+k (U = 4*br6(l)) have conjugate partners 256-(U+k):
//   k=0 -> lane p0 = br6((64-r6)&63), register x0
//   k=1 (reg x2) -> lane l^63, register x3
//   k=2 (reg x1) -> lane l^63, register x1
//   k=3 (reg x3) -> lane l^63, register x2
// Separation WITHOUT the 1/2 (A=Z+conj(P), B=-i(Z-conj(P))); the 1/2 is
// folded into Khat via a 0.25 scale on kprep's MLP output.
// ---------------------------------------------------------------------------

// ---------------------------------------------------------------------------
// kprep_col: grid CC*2. Block handles 64 columns of channel c. Packed pairs:
// z = k[:,2j] + i*k[:,2j+1]. MLP inline (scaled 0.25), packed col FFT,
// separate, natural-bin spectrum to LDS, coalesced write to Khat front half.
// ---------------------------------------------------------------------------
__global__ __launch_bounds__(512) void kprep_col(const float* __restrict__ W1,
                                                 const float* __restrict__ b1,
                                                 const float* __restrict__ W2,
                                                 const float* __restrict__ b2,
                                                 float2* __restrict__ Khat){
  __shared__ float sRe[NF*65];
  __shared__ float sIm[NF*65];
  const int S = 65;
  int t = threadIdx.x, l = t & 63, w = t >> 6;
  int c  = blockIdx.x >> 1;
  int q0B = (blockIdx.x & 1) * 64;
  Tw tw; tw_init(tw, l);
  int r6 = __brev((unsigned)l) >> 26;
  int l63 = l ^ 63;
  int p0 = __brev((unsigned)((64 - r6) & 63)) >> 26;

  float w1y[16], w1x[16], bb1[16], w2r[16];
#pragma unroll
  for (int h = 0; h < 16; ++h){
    w1y[h] = W1[h]; w1x[h] = W1[16+h]; bb1[h] = b1[h];
    w2r[h] = W2[h*CC + c] * 0.25f;          // 0.25 = fold both packings' 1/2
  }
  float bb2 = b2[c] * 0.25f;
  float gy0 = (float)l        * (1.0f/127.0f);
  float gy1 = (float)(l + 64) * (1.0f/127.0f);

#define SEPST32(Z, P, ROW) { \
  sRe[(ROW)*S + qa] = Z.x + P.x; sIm[(ROW)*S + qa] = Z.y - P.y; \
  sRe[(ROW)*S + qb] = Z.y + P.y; sIm[(ROW)*S + qb] = P.x - Z.x; }

  for (int ji = 0; ji < 4; ++ji){
    int jj = w*4 + ji;                      // pair index 0..31 (block-local)
    int qa = 2*jj, qb = 2*jj + 1;
    float gxa = (float)(q0B + qa) * (1.0f/127.0f);
    float gxb = (float)(q0B + qb) * (1.0f/127.0f);
    float a0 = bb2, a1 = bb2, bq0 = bb2, bq1 = bb2;
#pragma unroll
    for (int h = 0; h < 16; ++h){
      float hxa = gxa*w1x[h] + bb1[h];
      float hxb = gxb*w1x[h] + bb1[h];
      a0  += fmaxf(gy0*w1y[h] + hxa, 0.0f) * w2r[h];
      a1  += fmaxf(gy1*w1y[h] + hxa, 0.0f) * w2r[h];
      bq0 += fmaxf(gy0*w1y[h] + hxb, 0.0f) * w2r[h];
      bq1 += fmaxf(gy1*w1y[h] + hxb, 0.0f) * w2r[h];
    }
    float2 x0 = make_float2(a0, bq0);
    float2 x1 = make_float2(a1, bq1);
    float2 x2, x3;
    fft256_fwd_padded(x0, x1, x2, x3, tw, l);
    float2 f0p = shfli(x0, p0);
    float2 f2p = shfli(x3, l63);
    float2 f1p = shfli(x1, l63);
    float2 f3p = shfli(x2, l63);
    if (r6 <= 32){ SEPST32(x0, f0p, 4*r6); }
    if (r6 <= 31){
      SEPST32(x2, f2p, 4*r6+1);
      SEPST32(x1, f1p, 4*r6+2);
      SEPST32(x3, f3p, 4*r6+3);
    }
  }
#undef SEPST32
  __syncthreads();
  for (int idx = t; idx < NF*64; idx += 512){
    int u = idx >> 6, qq = idx & 63;
    Khat[((size_t)c*NF + u)*FN + q0B + qq] = make_float2(sRe[u*S+qq], sIm[u*S+qq]);
  }
}

// ---------------------------------------------------------------------------
// kprep_row: grid CC*4. Register-only in-place row FFTs on Khat rows.
// ---------------------------------------------------------------------------
__global__ __launch_bounds__(512) void kprep_row(float2* __restrict__ Khat){
  int t = threadIdx.x, l = t & 63, w = t >> 6;
  int c = blockIdx.x >> 2, part = blockIdx.x & 3;
  Tw tw; tw_init(tw, l);
  for (int j = w; ; j += 8){
    int u = part + 4*j;
    if (u >= NF) break;
    float2* kp = Khat + ((size_t)c*NF + u)*FN;
    float2 x0 = kp[l], x1 = kp[64 + l], x2, x3;
    fft256_fwd_padded(x0, x1, x2, x3, tw, l);
    kp[l] = x0; kp[64 + l] = x1; kp[128 + l] = x2; kp[192 + l] = x3;
  }
}

// ---------------------------------------------------------------------------
// fused_conv: one block per (b,c) image. Whole 2D FFT-conv in LDS.
// Steps 2 and 4 use real-pair packing: half the column FFTs.
// ---------------------------------------------------------------------------
__global__ __launch_bounds__(512) void fused_conv(const float* __restrict__ x,
                                                  const float2* __restrict__ Khat,
                                                  float* __restrict__ out){
  __shared__ unsigned short hRe[131*130];
  __shared__ unsigned short hIm[131*130];
  const int S = 130;
  int t = threadIdx.x, l = t & 63, w = t >> 6;
  int blk = blockIdx.x;
  int c = blk >> 4, b = blk & 15;        // 16 consecutive blocks share c (Khat L2 reuse)
  const float* xp = x   + ((size_t)b*CC + c)*(HH*WW);
  float*       yp = out + ((size_t)b*CC + c)*(HH*WW);
  Tw tw; tw_init(tw, l);
  int r6 = __brev((unsigned)l) >> 26;
  int l63 = l ^ 63;
  int p0 = __brev((unsigned)((64 - r6) & 63)) >> 26;

  // 1) x -> planes (exact fp32 split: hi16 in hRe, lo16 in hIm)
  for (int i = t; i < HH*WW; i += 512){
    int p = i >> 7, q = i & 127;
    unsigned int ub = __float_as_uint(xp[i]);
    hRe[p*S + q] = (unsigned short)(ub >> 16);
    hIm[p*S + q] = (unsigned short)(ub & 0xffffu);
  }
  __syncthreads();
  // 2) packed column forward FFTs (pairs 2j,2j+1); separate; store fp16 bins
#define SEPST16(Z, P, ROW) { \
  float ax_ = Z.x + P.x, ay_ = Z.y - P.y; \
  float bx_ = Z.y + P.y, by_ = P.x - Z.x; \
  *(ushort2*)&hRe[(ROW)*S + q0] = make_ushort2(f2h(ax_), f2h(bx_)); \
  *(ushort2*)&hIm[(ROW)*S + q0] = make_ushort2(f2h(ay_), f2h(by_)); }

  for (int ji = 0; ji < 8; ++ji){
    int jj = w*8 + ji;                     // pair index 0..63
    int q0 = 2*jj;
    ushort2 hr0 = *(const ushort2*)&hRe[l*S + q0];
    ushort2 hi0 = *(const ushort2*)&hIm[l*S + q0];
    ushort2 hr1 = *(const ushort2*)&hRe[(l+64)*S + q0];
    ushort2 hi1 = *(const ushort2*)&hIm[(l+64)*S + q0];
    float2 x0 = make_float2(__uint_as_float(((unsigned)hr0.x << 16) | hi0.x),
                            __uint_as_float(((unsigned)hr0.y << 16) | hi0.y));
    float2 x1 = make_float2(__uint_as_float(((unsigned)hr1.x << 16) | hi1.x),
                            __uint_as_float(((unsigned)hr1.y << 16) | hi1.y));
    float2 x2, x3;
    fft256_fwd_padded(x0, x1, x2, x3, tw, l);
    float2 f0p = shfli(x0, p0);
    float2 f2p = shfli(x3, l63);
    float2 f1p = shfli(x1, l63);
    float2 f3p = shfli(x2, l63);
    if (r6 <= 32){ SEPST16(x0, f0p, r6); }          // bin 4r6    -> row r6
    if (r6 <= 31){
      SEPST16(x2, f2p, 33+r6);                      // bin 4r6+1
      SEPST16(x1, f1p, 66+r6);                      // bin 4r6+2
      SEPST16(x3, f3p, 99+r6);                      // bin 4r6+3
    }
  }
#undef SEPST16
  __syncthreads();
  // 3) row conv: fwd -> x Khat -> inv+crop, in place (scaled 2^-10)
  for (int u = w; u < NF; u += 8){
    int pr = (u >> 2) + 33*(u & 3);
    float2 x0 = make_float2(h2f(hRe[pr*S + l]),      h2f(hIm[pr*S + l]));
    float2 x1 = make_float2(h2f(hRe[pr*S + 64 + l]), h2f(hIm[pr*S + 64 + l]));
    float2 x2, x3;
    fft256_fwd_padded(x0, x1, x2, x3, tw, l);
    const float2* kp = Khat + ((size_t)c*NF + u)*FN;
    x0 = cmul(x0, kp[l]);
    x1 = cmul(x1, kp[64 + l]);
    x2 = cmul(x2, kp[128 + l]);
    x3 = cmul(x3, kp[192 + l]);
    fft256_inv_crop(x0, x1, x2, x3, tw, l);
    hRe[pr*S + l]      = f2h(x0.x * SCL_DN); hIm[pr*S + l]      = f2h(x0.y * SCL_DN);
    hRe[pr*S + 64 + l] = f2h(x1.x * SCL_DN); hIm[pr*S + 64 + l] = f2h(x1.y * SCL_DN);
  }
  __syncthreads();
  // 4) packed column inverse: V[u] = Y[u][2j] + i*Y[u][2j+1] (Hermitian-
  //    extended per real column); IFFT; Re -> col 2j, Im -> col 2j+1.
#define GATHV(X, ROWA, ROWB, COND) { \
  int row_ = (COND) ? (ROWA) : (ROWB); \
  float s_ = (COND) ? -1.0f : 1.0f; \
  ushort2 hr_ = *(const ushort2*)&hRe[row_*S + q0]; \
  ushort2 hi_ = *(const ushort2*)&hIm[row_*S + q0]; \
  float re0_ = h2f(hr_.x), re1_ = h2f(hr_.y); \
  float im0_ = h2f(hi_.x), im1_ = h2f(hi_.y); \
  X = make_float2(fmaf(s_, im1_, re0_), fmaf(-s_, im0_, re1_)); }

  for (int ji = 0; ji < 8; ++ji){
    int jj = w*8 + ji;
    int q0 = 2*jj;
    float2 x0, x1, x2, x3;
    GATHV(x0, r6,    64-r6,  r6 <= 32);    // bins 4r6
    GATHV(x2, 33+r6, 162-r6, r6 <= 31);    // bins 4r6+1
    GATHV(x1, 66+r6, 129-r6, r6 <= 31);    // bins 4r6+2
    GATHV(x3, 99+r6, 96-r6,  r6 <= 31);    // bins 4r6+3
    fft256_inv_crop(x0, x1, x2, x3, tw, l);
    unsigned ua0 = __float_as_uint(x0.x * SCL_UP);
    unsigned ub0 = __float_as_uint(x0.y * SCL_UP);
    *(ushort2*)&hRe[l*S + q0] = make_ushort2((unsigned short)(ua0 >> 16), (unsigned short)(ub0 >> 16));
    *(ushort2*)&hIm[l*S + q0] = make_ushort2((unsigned short)(ua0 & 0xffffu), (unsigned short)(ub0 & 0xffffu));
    unsigned ua1 = __float_as_uint(x1.x * SCL_UP);
    unsigned ub1 = __float_as_uint(x1.y * SCL_UP);
    *(ushort2*)&hRe[(l+64)*S + q0] = make_ushort2((unsigned short)(ua1 >> 16), (unsigned short)(ub1 >> 16));
    *(ushort2*)&hIm[(l+64)*S + q0] = make_ushort2((unsigned short)(ua1 & 0xffffu), (unsigned short)(ub1 & 0xffffu));
  }
#undef GATHV
  __syncthreads();
  // 5) out = y + x (coalesced)
  for (int i = t; i < HH*WW; i += 512){
    int p = i >> 7, q = i & 127;
    unsigned int ub = ((unsigned int)hRe[p*S + q] << 16) | hIm[p*S + q];
    yp[i] = __uint_as_float(ub) + xp[i];
  }
}

// ---------------------------------------------------------------------------
// Host launcher
// ---------------------------------------------------------------------------
extern "C" void kernel_launch(void* const* d_in, const int* in_sizes, int n_in,
                              void* d_out, int out_size, void* d_ws, size_t ws_size,
                              hipStream_t stream) {
  const float* x  = (const float*)d_in[0];
  const float* W1 = (const float*)d_in[1];
  const float* b1 = (const float*)d_in[2];
  const float* W2 = (const float*)d_in[3];
  const float* b2 = (const float*)d_in[4];
  float* out = (float*)d_out;

  float2* Khat = (float2*)d_ws;   // CC*NF*FN complex = 25.4 MB

  kprep_col<<<CC*2, 512, 0, stream>>>(W1, b1, W2, b2, Khat);
  kprep_row<<<CC*4, 512, 0, stream>>>(Khat);
  fused_conv<<<CC*BB, 512, 0, stream>>>(x, Khat, out);
}

// Round 5
// 421.485 us; speedup vs baseline: 1.6209x; 1.0086x over previous
//
#include <hip/hip_runtime.h>
#include <hip/hip_fp16.h>

#define TWO_PI 6.283185307179586f
#define PI_F   3.14159265358979f

// Problem constants
#define HH 128      // H
#define WW 128      // W
#define FN 256      // padded FFT size (2H)
#define NF 129      // FN/2+1 vertical frequency bins
#define CC 96
#define BB 16

#define SCL_DN 0.0009765625f   // 2^-10 : scale on row-conv output before fp16 store
#define SCL_UP 1024.0f

typedef unsigned int uint2v __attribute__((ext_vector_type(2)));
typedef __fp16 half2v __attribute__((ext_vector_type(2)));

__device__ __forceinline__ float2 cmul(float2 a, float2 b){
  return make_float2(a.x*b.x - a.y*b.y, a.x*b.y + a.y*b.x);
}
__device__ __forceinline__ float2 cmulc(float2 a, float2 b){   // conj(a)*b
  return make_float2(a.x*b.x + a.y*b.y, a.x*b.y - a.y*b.x);
}
__device__ __forceinline__ float2 cadd(float2 a, float2 b){ return make_float2(a.x+b.x, a.y+b.y); }
__device__ __forceinline__ float2 csub(float2 a, float2 b){ return make_float2(a.x-b.x, a.y-b.y); }
__device__ __forceinline__ float2 shflx(float2 v, int m){
  float2 r; r.x = __shfl_xor(v.x, m, 64); r.y = __shfl_xor(v.y, m, 64); return r;
}
__device__ __forceinline__ float2 shfli(float2 v, int idx){
  float2 r; r.x = __shfl(v.x, idx, 64); r.y = __shfl(v.y, idx, 64); return r;
}
__device__ __forceinline__ unsigned short f2h(float v){ return __half_as_ushort(__float2half(v)); }
__device__ __forceinline__ float h2f(unsigned short u){ return __half2float(__ushort_as_half(u)); }
// packed fp16 helpers for the interleaved u32 LDS plane
__device__ __forceinline__ unsigned pkh2(float a, float b){
  union { half2v h; unsigned u; } cv;
  cv.h = __builtin_amdgcn_cvt_pkrtz(a, b);     // v_cvt_pkrtz_f16_f32: lo=a, hi=b
  return cv.u;
}
__device__ __forceinline__ float h2lo(unsigned u){ return h2f((unsigned short)(u & 0xffffu)); }
__device__ __forceinline__ float h2hi(unsigned u){ return h2f((unsigned short)(u >> 16)); }

// ---------------------------------------------------------------------------
// Cross-lane exchange helpers on the VALU pipe (gfx950): permlane32/16 swaps
// give both halves; DPP quad_perm for xor-1/xor-2. h=8/h=4 stay ds_swizzle
// (DS pipe has large headroom; VALU is the binding pipe).
// ---------------------------------------------------------------------------
__device__ __forceinline__ void swp32(float2 v, float2& lo, float2& hi){
  uint2v rx = __builtin_amdgcn_permlane32_swap(__float_as_uint(v.x), __float_as_uint(v.x), false, false);
  uint2v ry = __builtin_amdgcn_permlane32_swap(__float_as_uint(v.y), __float_as_uint(v.y), false, false);
  lo = make_float2(__uint_as_float(rx[0]), __uint_as_float(ry[0]));
  hi = make_float2(__uint_as_float(rx[1]), __uint_as_float(ry[1]));
}
__device__ __forceinline__ void swp16(float2 v, float2& lo, float2& hi){
  uint2v rx = __builtin_amdgcn_permlane16_swap(__float_as_uint(v.x), __float_as_uint(v.x), false, false);
  uint2v ry = __builtin_amdgcn_permlane16_swap(__float_as_uint(v.y), __float_as_uint(v.y), false, false);
  lo = make_float2(__uint_as_float(rx[0]), __uint_as_float(ry[0]));
  hi = make_float2(__uint_as_float(rx[1]), __uint_as_float(ry[1]));
}
template<int CTRL>
__device__ __forceinline__ float2 dppx(float2 v){
  float2 r;
  r.x = __uint_as_float((unsigned)__builtin_amdgcn_update_dpp(0, (int)__float_as_uint(v.x), CTRL, 0xF, 0xF, true));
  r.y = __uint_as_float((unsigned)__builtin_amdgcn_update_dpp(0, (int)__float_as_uint(v.y), CTRL, 0xF, 0xF, true));
  return r;
}
#define DPP_XOR1 0xB1   // quad_perm [1,0,3,2]
#define DPP_XOR2 0x4E   // quad_perm [2,3,0,1]

// ---------------------------------------------------------------------------
// Wave-resident 256-pt FFT. Lane l holds positions l, l+64, l+128, l+192.
// Forward DIF output: lane l holds natural bins 4*br6(l)+{0,1,2,3} in regs
// (x0, x2, x1, x3). Select-free butterflies with per-lane precomputed
// sigma / twiddle (Tw).
// ---------------------------------------------------------------------------
struct Tw {
  float2 w128a, w128b, w64;
  float2 wc[5];   // raw stage twiddles, h = 32,16,8,4,2
  float2 wf[5];   // forward per-lane post-multiplier: (l&h)? wc : (1,0)
  float  sg[5];   // (l&h) ? -1 : +1
  float  sg1;     // (l&1) ? -1 : +1
};

__device__ __forceinline__ void tw_init(Tw& t, int l){
  float s, c;
  sincosf(-TWO_PI * (float)l * (1.0f/256.0f), &s, &c);
  t.w128a = make_float2(c, s);                 // W256^l
  t.w128b = make_float2(s, -c);                // W256^(l+64)
  t.w64   = make_float2(c*c - s*s, 2.0f*c*s);  // W256^(2l)
  const int hs[5] = {32,16,8,4,2};
#pragma unroll
  for (int i = 0; i < 5; ++i){
    int h = hs[i];
    float ang = -PI_F * (float)(l & (h-1)) / (float)h;
    sincosf(ang, &s, &c);
    t.wc[i] = make_float2(c, s);
    bool dn = (l & h) != 0;
    t.wf[i] = dn ? t.wc[i] : make_float2(1.0f, 0.0f);
    t.sg[i] = dn ? -1.0f : 1.0f;
  }
  t.sg1 = (l & 1) ? -1.0f : 1.0f;
}

// forward exchange, partner-value form (ds_swizzle / DPP stages)
#define FX_OTHER(X, OTHER, SG, WF) { \
  float2 o_ = OTHER; float2 s_; \
  s_.x = fmaf(SG, X.x, o_.x); s_.y = fmaf(SG, X.y, o_.y); \
  X = cmul(WF, s_); }
// forward exchange, both-halves form (permlane stages)
#define FX_LOHI(X, SWPF, SG, WF) { \
  float2 lo_, hi_, s_; SWPF(X, lo_, hi_); \
  s_.x = fmaf(SG, hi_.x, lo_.x); s_.y = fmaf(SG, hi_.y, lo_.y); \
  X = cmul(WF, s_); }
// inverse exchange, both-halves form:  x = lo + sg * (conj(w) * hi)
#define IX_LOHI(X, SWPF, SG, WC) { \
  float2 lo_, hi_, m_; SWPF(X, lo_, hi_); \
  m_ = cmulc(WC, hi_); \
  X.x = fmaf(SG, m_.x, lo_.x); X.y = fmaf(SG, m_.y, lo_.y); }
// inverse exchange, partner form (needs role swap)
#define IX_OTHER(X, OTHER, UP, SG, WC) { \
  float2 o_ = OTHER; \
  float2 A_ = UP ? X : o_; \
  float2 B_ = UP ? o_ : X; \
  float2 m_ = cmulc(WC, B_); \
  X.x = fmaf(SG, m_.x, A_.x); X.y = fmaf(SG, m_.y, A_.y); }

__device__ __forceinline__ void fft256_fwd_padded(float2& x0, float2& x1,
                                                  float2& x2, float2& x3,
                                                  const Tw& t, int l){
  x2 = cmul(x0, t.w128a);
  x3 = cmul(x1, t.w128b);
  float2 a = x0, b = x1;
  x0 = cadd(a, b); x1 = cmul(csub(a, b), t.w64);
  a = x2; b = x3;
  x2 = cadd(a, b); x3 = cmul(csub(a, b), t.w64);
  // h = 32 : permlane32_swap (VALU)
  FX_LOHI(x0, swp32, t.sg[0], t.wf[0]);
  FX_LOHI(x1, swp32, t.sg[0], t.wf[0]);
  FX_LOHI(x2, swp32, t.sg[0], t.wf[0]);
  FX_LOHI(x3, swp32, t.sg[0], t.wf[0]);
  // h = 16 : permlane16_swap (VALU)
  FX_LOHI(x0, swp16, t.sg[1], t.wf[1]);
  FX_LOHI(x1, swp16, t.sg[1], t.wf[1]);
  FX_LOHI(x2, swp16, t.sg[1], t.wf[1]);
  FX_LOHI(x3, swp16, t.sg[1], t.wf[1]);
  // h = 8, 4 : ds_swizzle
  FX_OTHER(x0, shflx(x0, 8), t.sg[2], t.wf[2]);
  FX_OTHER(x1, shflx(x1, 8), t.sg[2], t.wf[2]);
  FX_OTHER(x2, shflx(x2, 8), t.sg[2], t.wf[2]);
  FX_OTHER(x3, shflx(x3, 8), t.sg[2], t.wf[2]);
  FX_OTHER(x0, shflx(x0, 4), t.sg[3], t.wf[3]);
  FX_OTHER(x1, shflx(x1, 4), t.sg[3], t.wf[3]);
  FX_OTHER(x2, shflx(x2, 4), t.sg[3], t.wf[3]);
  FX_OTHER(x3, shflx(x3, 4), t.sg[3], t.wf[3]);
  // h = 2 : DPP quad_perm (VALU)
  FX_OTHER(x0, dppx<DPP_XOR2>(x0), t.sg[4], t.wf[4]);
  FX_OTHER(x1, dppx<DPP_XOR2>(x1), t.sg[4], t.wf[4]);
  FX_OTHER(x2, dppx<DPP_XOR2>(x2), t.sg[4], t.wf[4]);
  FX_OTHER(x3, dppx<DPP_XOR2>(x3), t.sg[4], t.wf[4]);
  // h = 1 : DPP quad_perm, no twiddle
  {
    float2 o;
    o = dppx<DPP_XOR1>(x0); x0.x = fmaf(t.sg1, x0.x, o.x); x0.y = fmaf(t.sg1, x0.y, o.y);
    o = dppx<DPP_XOR1>(x1); x1.x = fmaf(t.sg1, x1.x, o.x); x1.y = fmaf(t.sg1, x1.y, o.y);
    o = dppx<DPP_XOR1>(x2); x2.x = fmaf(t.sg1, x2.x, o.x); x2.y = fmaf(t.sg1, x2.y, o.y);
    o = dppx<DPP_XOR1>(x3); x3.x = fmaf(t.sg1, x3.x, o.x); x3.y = fmaf(t.sg1, x3.y, o.y);
  }
}

__device__ __forceinline__ void fft256_inv_crop(float2& x0, float2& x1,
                                                float2& x2, float2& x3,
                                                const Tw& t, int l){
  // h = 1 : DPP, no twiddle
  {
    float2 o;
    o = dppx<DPP_XOR1>(x0); x0.x = fmaf(t.sg1, x0.x, o.x); x0.y = fmaf(t.sg1, x0.y, o.y);
    o = dppx<DPP_XOR1>(x1); x1.x = fmaf(t.sg1, x1.x, o.x); x1.y = fmaf(t.sg1, x1.y, o.y);
    o = dppx<DPP_XOR1>(x2); x2.x = fmaf(t.sg1, x2.x, o.x); x2.y = fmaf(t.sg1, x2.y, o.y);
    o = dppx<DPP_XOR1>(x3); x3.x = fmaf(t.sg1, x3.x, o.x); x3.y = fmaf(t.sg1, x3.y, o.y);
  }
  // h = 2 : DPP
  {
    bool up = (l & 2) == 0;
    IX_OTHER(x0, dppx<DPP_XOR2>(x0), up, t.sg[4], t.wc[4]);
    IX_OTHER(x1, dppx<DPP_XOR2>(x1), up, t.sg[4], t.wc[4]);
    IX_OTHER(x2, dppx<DPP_XOR2>(x2), up, t.sg[4], t.wc[4]);
    IX_OTHER(x3, dppx<DPP_XOR2>(x3), up, t.sg[4], t.wc[4]);
  }
  // h = 4, 8 : ds_swizzle
  {
    bool up = (l & 4) == 0;
    IX_OTHER(x0, shflx(x0, 4), up, t.sg[3], t.wc[3]);
    IX_OTHER(x1, shflx(x1, 4), up, t.sg[3], t.wc[3]);
    IX_OTHER(x2, shflx(x2, 4), up, t.sg[3], t.wc[3]);
    IX_OTHER(x3, shflx(x3, 4), up, t.sg[3], t.wc[3]);
  }
  {
    bool up = (l & 8) == 0;
    IX_OTHER(x0, shflx(x0, 8), up, t.sg[2], t.wc[2]);
    IX_OTHER(x1, shflx(x1, 8), up, t.sg[2], t.wc[2]);
    IX_OTHER(x2, shflx(x2, 8), up, t.sg[2], t.wc[2]);
    IX_OTHER(x3, shflx(x3, 8), up, t.sg[2], t.wc[2]);
  }
  // h = 16 : permlane16_swap
  IX_LOHI(x0, swp16, t.sg[1], t.wc[1]);
  IX_LOHI(x1, swp16, t.sg[1], t.wc[1]);
  IX_LOHI(x2, swp16, t.sg[1], t.wc[1]);
  IX_LOHI(x3, swp16, t.sg[1], t.wc[1]);
  // h = 32 : permlane32_swap
  IX_LOHI(x0, swp32, t.sg[0], t.wc[0]);
  IX_LOHI(x1, swp32, t.sg[0], t.wc[0]);
  IX_LOHI(x2, swp32, t.sg[0], t.wc[0]);
  IX_LOHI(x3, swp32, t.sg[0], t.wc[0]);
  {
    float2 w = make_float2(t.w64.x, -t.w64.y);
    float2 t0 = cmul(w, x1); x1 = csub(x0, t0); x0 = cadd(x0, t0);
    float2 t1 = cmul(w, x3); x3 = csub(x2, t1); x2 = cadd(x2, t1);
  }
  {
    float2 wa = make_float2(t.w128a.x, -t.w128a.y);
    float2 wb = make_float2(t.w128b.x, -t.w128b.y);
    x0 = cadd(x0, cmul(wa, x2));
    x1 = cadd(x1, cmul(wb, x3));
  }
}

// ---------------------------------------------------------------------------
// Conjugate-partner map (bin U+k, U = 4*br6(l)):
//   k=0 -> lane p0 = br6((64-r6)&63), reg x0
//   k=1 (reg x2) -> lane l^63, reg x3
//   k=2 (reg x1) -> lane l^63, reg x1
//   k=3 (reg x3) -> lane l^63, reg x2
// ---------------------------------------------------------------------------

// ---------------------------------------------------------------------------
// kprep_col: grid CC*2. Packed real-pair column FFTs of the MLP kernel
// (scaled 0.25 = both packings' 1/2), natural-bin spectrum to LDS, coalesced
// write to Khat front half.
// ---------------------------------------------------------------------------
__global__ __launch_bounds__(512) void kprep_col(const float* __restrict__ W1,
                                                 const float* __restrict__ b1,
                                                 const float* __restrict__ W2,
                                                 const float* __restrict__ b2,
                                                 float2* __restrict__ Khat){
  __shared__ float sRe[NF*65];
  __shared__ float sIm[NF*65];
  const int S = 65;
  int t = threadIdx.x, l = t & 63, w = t >> 6;
  int c  = blockIdx.x >> 1;
  int q0B = (blockIdx.x & 1) * 64;
  Tw tw; tw_init(tw, l);
  int r6 = __brev((unsigned)l) >> 26;
  int l63 = l ^ 63;
  int p0 = __brev((unsigned)((64 - r6) & 63)) >> 26;

  float w1y[16], w1x[16], bb1[16], w2r[16];
#pragma unroll
  for (int h = 0; h < 16; ++h){
    w1y[h] = W1[h]; w1x[h] = W1[16+h]; bb1[h] = b1[h];
    w2r[h] = W2[h*CC + c] * 0.25f;
  }
  float bb2 = b2[c] * 0.25f;
  float gy0 = (float)l        * (1.0f/127.0f);
  float gy1 = (float)(l + 64) * (1.0f/127.0f);

#define SEPST32(Z, P, ROW) { \
  sRe[(ROW)*S + qa] = Z.x + P.x; sIm[(ROW)*S + qa] = Z.y - P.y; \
  sRe[(ROW)*S + qb] = Z.y + P.y; sIm[(ROW)*S + qb] = P.x - Z.x; }

  for (int ji = 0; ji < 4; ++ji){
    int jj = w*4 + ji;
    int qa = 2*jj, qb = 2*jj + 1;
    float gxa = (float)(q0B + qa) * (1.0f/127.0f);
    float gxb = (float)(q0B + qb) * (1.0f/127.0f);
    float a0 = bb2, a1 = bb2, bq0 = bb2, bq1 = bb2;
#pragma unroll
    for (int h = 0; h < 16; ++h){
      float hxa = gxa*w1x[h] + bb1[h];
      float hxb = gxb*w1x[h] + bb1[h];
      a0  += fmaxf(gy0*w1y[h] + hxa, 0.0f) * w2r[h];
      a1  += fmaxf(gy1*w1y[h] + hxa, 0.0f) * w2r[h];
      bq0 += fmaxf(gy0*w1y[h] + hxb, 0.0f) * w2r[h];
      bq1 += fmaxf(gy1*w1y[h] + hxb, 0.0f) * w2r[h];
    }
    float2 x0 = make_float2(a0, bq0);
    float2 x1 = make_float2(a1, bq1);
    float2 x2, x3;
    fft256_fwd_padded(x0, x1, x2, x3, tw, l);
    float2 f0p = shfli(x0, p0);
    float2 f2p = shfli(x3, l63);
    float2 f1p = shfli(x1, l63);
    float2 f3p = shfli(x2, l63);
    if (r6 <= 32){ SEPST32(x0, f0p, 4*r6); }
    if (r6 <= 31){
      SEPST32(x2, f2p, 4*r6+1);
      SEPST32(x1, f1p, 4*r6+2);
      SEPST32(x3, f3p, 4*r6+3);
    }
  }
#undef SEPST32
  __syncthreads();
  for (int idx = t; idx < NF*64; idx += 512){
    int u = idx >> 6, qq = idx & 63;
    Khat[((size_t)c*NF + u)*FN + q0B + qq] = make_float2(sRe[u*S+qq], sIm[u*S+qq]);
  }
}

// ---------------------------------------------------------------------------
// kprep_row: grid CC*4. Register-only in-place row FFTs on Khat rows.
// ---------------------------------------------------------------------------
__global__ __launch_bounds__(512) void kprep_row(float2* __restrict__ Khat){
  int t = threadIdx.x, l = t & 63, w = t >> 6;
  int c = blockIdx.x >> 2, part = blockIdx.x & 3;
  Tw tw; tw_init(tw, l);
  for (int j = w; ; j += 8){
    int u = part + 4*j;
    if (u >= NF) break;
    float2* kp = Khat + ((size_t)c*NF + u)*FN;
    float2 x0 = kp[l], x1 = kp[64 + l], x2, x3;
    fft256_fwd_padded(x0, x1, x2, x3, tw, l);
    kp[l] = x0; kp[64 + l] = x1; kp[128 + l] = x2; kp[192 + l] = x3;
  }
}

// ---------------------------------------------------------------------------
// fused_conv: one block per (b,c) image. Whole 2D FFT-conv in LDS.
// Single interleaved u32 LDS plane:
//   - x / y phases: PL[p][q] = raw fp32 bits (exact)
//   - spectra phases: PL[row][q] = half2 (re lo16, im hi16), cmap rows
// Step 3 packs the exactly-real rows u=0 and u=128 into one complex FFT
// -> 16 perfectly balanced row-conv tasks per wave.
// ---------------------------------------------------------------------------
__global__ __launch_bounds__(512) void fused_conv(const float* __restrict__ x,
                                                  const float2* __restrict__ Khat,
                                                  float* __restrict__ out){
  __shared__ unsigned int PL[131*130];
  const int S = 130;
  int t = threadIdx.x, l = t & 63, w = t >> 6;
  int blk = blockIdx.x;
  int c = blk >> 4, b = blk & 15;        // 16 consecutive blocks share c (Khat L2 reuse)
  const float* xp = x   + ((size_t)b*CC + c)*(HH*WW);
  float*       yp = out + ((size_t)b*CC + c)*(HH*WW);
  Tw tw; tw_init(tw, l);
  int r6 = __brev((unsigned)l) >> 26;
  int l63 = l ^ 63;
  int p0 = __brev((unsigned)((64 - r6) & 63)) >> 26;

  // 1) x -> raw fp32 bits
  for (int i = t; i < HH*WW; i += 512){
    int p = i >> 7, q = i & 127;
    PL[p*S + q] = __float_as_uint(xp[i]);
  }
  __syncthreads();
  // 2) packed column forward FFTs (cols 2j,2j+1); separate; store half2 bins
#define SEPST16(Z, P, ROW) { \
  uint2 st_; \
  st_.x = pkh2(Z.x + P.x, Z.y - P.y); \
  st_.y = pkh2(Z.y + P.y, P.x - Z.x); \
  *(uint2*)&PL[(ROW)*S + q0] = st_; }

  for (int ji = 0; ji < 8; ++ji){
    int jj = w*8 + ji;                     // pair index 0..63
    int q0 = 2*jj;
    uint2 v0 = *(const uint2*)&PL[l*S + q0];
    uint2 v1 = *(const uint2*)&PL[(l+64)*S + q0];
    float2 x0 = make_float2(__uint_as_float(v0.x), __uint_as_float(v0.y));
    float2 x1 = make_float2(__uint_as_float(v1.x), __uint_as_float(v1.y));
    float2 x2, x3;
    fft256_fwd_padded(x0, x1, x2, x3, tw, l);
    float2 f0p = shfli(x0, p0);
    float2 f2p = shfli(x3, l63);
    float2 f1p = shfli(x1, l63);
    float2 f3p = shfli(x2, l63);
    if (r6 <= 32){ SEPST16(x0, f0p, r6); }          // bin 4r6    -> row r6
    if (r6 <= 31){
      SEPST16(x2, f2p, 33+r6);                      // bin 4r6+1
      SEPST16(x1, f1p, 66+r6);                      // bin 4r6+2
      SEPST16(x3, f3p, 99+r6);                      // bin 4r6+3
    }
  }
#undef SEPST16
  __syncthreads();
  // 3) row conv, 16 balanced tasks/wave. Wave 0 task 0 = packed rows (0,128).
  for (int k = 0; k < 16; ++k){
    int u = w + 8*k;
    if (w == 0 && k == 0){
      // -------- packed real rows u=0 (pr=0) and u=128 (pr=32) --------
      unsigned a0 = PL[l],           a1 = PL[64 + l];        // row 0
      unsigned c0 = PL[32*S + l],    c1 = PL[32*S + 64 + l]; // row 32
      float2 x0 = make_float2(h2lo(a0), h2lo(c0));
      float2 x1 = make_float2(h2lo(a1), h2lo(c1));
      float2 x2, x3;
      fft256_fwd_padded(x0, x1, x2, x3, tw, l);
      float2 f0p = shfli(x0, p0);
      float2 f2p = shfli(x3, l63);
      float2 f1p = shfli(x1, l63);
      float2 f3p = shfli(x2, l63);
      const float2* k0p = Khat + (size_t)c*NF*FN;        // u = 0
      const float2* k1p = k0p + (size_t)128*FN;          // u = 128
#define PKMUL(Z, P, OFF) { \
      float2 A2_ = make_float2(Z.x + P.x, Z.y - P.y); \
      float2 B2_ = make_float2(Z.y + P.y, P.x - Z.x); \
      float2 m0_ = cmul(A2_, k0p[OFF]); \
      float2 m1_ = cmul(B2_, k1p[OFF]); \
      Z = make_float2(m0_.x - m1_.y, m0_.y + m1_.x); }
      PKMUL(x0, f0p, l);
      PKMUL(x2, f2p, 128 + l);
      PKMUL(x1, f1p, 64 + l);
      PKMUL(x3, f3p, 192 + l);
#undef PKMUL
      fft256_inv_crop(x0, x1, x2, x3, tw, l);
      const float sc = SCL_DN * 0.5f;      // extra 1/2 from this packing
      PL[l]           = pkh2(x0.x * sc, 0.0f);   // Y[0][l]   (real)
      PL[32*S + l]    = pkh2(x0.y * sc, 0.0f);   // Y[128][l] (real)
      PL[64 + l]      = pkh2(x1.x * sc, 0.0f);
      PL[32*S + 64+l] = pkh2(x1.y * sc, 0.0f);
    } else {
      int pr = (u >> 2) + 33*(u & 3);
      unsigned ua = PL[pr*S + l];
      unsigned ub = PL[pr*S + 64 + l];
      float2 x0 = make_float2(h2lo(ua), h2hi(ua));
      float2 x1 = make_float2(h2lo(ub), h2hi(ub));
      float2 x2, x3;
      fft256_fwd_padded(x0, x1, x2, x3, tw, l);
      const float2* kp = Khat + ((size_t)c*NF + u)*FN;
      x0 = cmul(x0, kp[l]);
      x1 = cmul(x1, kp[64 + l]);
      x2 = cmul(x2, kp[128 + l]);
      x3 = cmul(x3, kp[192 + l]);
      fft256_inv_crop(x0, x1, x2, x3, tw, l);
      PL[pr*S + l]      = pkh2(x0.x * SCL_DN, x0.y * SCL_DN);
      PL[pr*S + 64 + l] = pkh2(x1.x * SCL_DN, x1.y * SCL_DN);
    }
  }
  __syncthreads();
  // 4) packed column inverse (Hermitian gather by natural bin) + crop -> y bits
#define GATHV(X, ROWA, ROWB, COND) { \
  int row_ = (COND) ? (ROWA) : (ROWB); \
  float s_ = (COND) ? -1.0f : 1.0f; \
  uint2 u_ = *(const uint2*)&PL[row_*S + q0]; \
  X = make_float2(fmaf(s_, h2hi(u_.y), h2lo(u_.x)), \
                  fmaf(-s_, h2hi(u_.x), h2lo(u_.y))); }

  for (int ji = 0; ji < 8; ++ji){
    int jj = w*8 + ji;
    int q0 = 2*jj;
    float2 x0, x1, x2, x3;
    GATHV(x0, r6,    64-r6,  r6 <= 32);    // bins 4r6
    GATHV(x2, 33+r6, 162-r6, r6 <= 31);    // bins 4r6+1
    GATHV(x1, 66+r6, 129-r6, r6 <= 31);    // bins 4r6+2
    GATHV(x3, 99+r6, 96-r6,  r6 <= 31);    // bins 4r6+3
    fft256_inv_crop(x0, x1, x2, x3, tw, l);
    uint2 st0, st1;
    st0.x = __float_as_uint(x0.x * SCL_UP);
    st0.y = __float_as_uint(x0.y * SCL_UP);
    *(uint2*)&PL[l*S + q0] = st0;
    st1.x = __float_as_uint(x1.x * SCL_UP);
    st1.y = __float_as_uint(x1.y * SCL_UP);
    *(uint2*)&PL[(l+64)*S + q0] = st1;
  }
#undef GATHV
  __syncthreads();
  // 5) out = y + x (coalesced)
  for (int i = t; i < HH*WW; i += 512){
    int p = i >> 7, q = i & 127;
    yp[i] = __uint_as_float(PL[p*S + q]) + xp[i];
  }
}

// ---------------------------------------------------------------------------
// Host launcher
// ---------------------------------------------------------------------------
extern "C" void kernel_launch(void* const* d_in, const int* in_sizes, int n_in,
                              void* d_out, int out_size, void* d_ws, size_t ws_size,
                              hipStream_t stream) {
  const float* x  = (const float*)d_in[0];
  const float* W1 = (const float*)d_in[1];
  const float* b1 = (const float*)d_in[2];
  const float* W2 = (const float*)d_in[3];
  const float* b2 = (const float*)d_in[4];
  float* out = (float*)d_out;

  float2* Khat = (float2*)d_ws;   // CC*NF*FN complex = 25.4 MB

  kprep_col<<<CC*2, 512, 0, stream>>>(W1, b1, W2, b2, Khat);
  kprep_row<<<CC*4, 512, 0, stream>>>(Khat);
  fused_conv<<<CC*BB, 512, 0, stream>>>(x, Khat, out);
}

// Round 7
// 419.643 us; speedup vs baseline: 1.6280x; 1.0044x over previous
//
#include <hip/hip_runtime.h>
#include <hip/hip_fp16.h>

#define TWO_PI 6.283185307179586f
#define PI_F   3.14159265358979f

// Problem constants
#define HH 128      // H
#define WW 128      // W
#define FN 256      // padded FFT size (2H)
#define NF 129      // FN/2+1 vertical frequency bins
#define CC 96
#define BB 16

#define SCL_DN 0.0009765625f   // 2^-10 : scale on row-conv output before fp16 store
#define SCL_UP 1024.0f

typedef unsigned int uint2v __attribute__((ext_vector_type(2)));
typedef __fp16 half2v __attribute__((ext_vector_type(2)));

__device__ __forceinline__ float2 cmul(float2 a, float2 b){
  return make_float2(a.x*b.x - a.y*b.y, a.x*b.y + a.y*b.x);
}
__device__ __forceinline__ float2 cmulc(float2 a, float2 b){   // conj(a)*b
  return make_float2(a.x*b.x + a.y*b.y, a.x*b.y - a.y*b.x);
}
__device__ __forceinline__ float2 cadd(float2 a, float2 b){ return make_float2(a.x+b.x, a.y+b.y); }
__device__ __forceinline__ float2 csub(float2 a, float2 b){ return make_float2(a.x-b.x, a.y-b.y); }
__device__ __forceinline__ float2 shflx(float2 v, int m){
  float2 r; r.x = __shfl_xor(v.x, m, 64); r.y = __shfl_xor(v.y, m, 64); return r;
}
__device__ __forceinline__ float2 shfli(float2 v, int idx){
  float2 r; r.x = __shfl(v.x, idx, 64); r.y = __shfl(v.y, idx, 64); return r;
}
__device__ __forceinline__ unsigned short f2h(float v){ return __half_as_ushort(__float2half(v)); }
__device__ __forceinline__ float h2f(unsigned short u){ return __half2float(__ushort_as_half(u)); }
// packed fp16 helpers for the interleaved u32 LDS plane
__device__ __forceinline__ unsigned pkh2(float a, float b){
  union { half2v h; unsigned u; } cv;
  cv.h = __builtin_amdgcn_cvt_pkrtz(a, b);     // v_cvt_pkrtz_f16_f32: lo=a, hi=b
  return cv.u;
}
__device__ __forceinline__ float h2lo(unsigned u){ return h2f((unsigned short)(u & 0xffffu)); }
__device__ __forceinline__ float h2hi(unsigned u){ return h2f((unsigned short)(u >> 16)); }

// ---------------------------------------------------------------------------
// Cross-lane exchange helpers on the VALU pipe (gfx950): permlane32/16 swaps
// give both halves; DPP quad_perm for xor-1/xor-2. h=8/h=4 stay ds_swizzle
// (DS pipe has headroom; VALU is the binding pipe).
// ---------------------------------------------------------------------------
__device__ __forceinline__ void swp32(float2 v, float2& lo, float2& hi){
  uint2v rx = __builtin_amdgcn_permlane32_swap(__float_as_uint(v.x), __float_as_uint(v.x), false, false);
  uint2v ry = __builtin_amdgcn_permlane32_swap(__float_as_uint(v.y), __float_as_uint(v.y), false, false);
  lo = make_float2(__uint_as_float(rx[0]), __uint_as_float(ry[0]));
  hi = make_float2(__uint_as_float(rx[1]), __uint_as_float(ry[1]));
}
__device__ __forceinline__ void swp16(float2 v, float2& lo, float2& hi){
  uint2v rx = __builtin_amdgcn_permlane16_swap(__float_as_uint(v.x), __float_as_uint(v.x), false, false);
  uint2v ry = __builtin_amdgcn_permlane16_swap(__float_as_uint(v.y), __float_as_uint(v.y), false, false);
  lo = make_float2(__uint_as_float(rx[0]), __uint_as_float(ry[0]));
  hi = make_float2(__uint_as_float(rx[1]), __uint_as_float(ry[1]));
}
template<int CTRL>
__device__ __forceinline__ float2 dppx(float2 v){
  float2 r;
  r.x = __uint_as_float((unsigned)__builtin_amdgcn_update_dpp(0, (int)__float_as_uint(v.x), CTRL, 0xF, 0xF, true));
  r.y = __uint_as_float((unsigned)__builtin_amdgcn_update_dpp(0, (int)__float_as_uint(v.y), CTRL, 0xF, 0xF, true));
  return r;
}
#define DPP_XOR1 0xB1   // quad_perm [1,0,3,2]
#define DPP_XOR2 0x4E   // quad_perm [2,3,0,1]

// ---------------------------------------------------------------------------
// Wave-resident 256-pt FFT. Lane l holds positions l, l+64, l+128, l+192.
// Forward DIF output: lane l holds natural bins 4*br6(l)+{0,1,2,3} in regs
// (x0, x2, x1, x3). Select-free butterflies with per-lane precomputed
// sigma / twiddle (Tw).
// ---------------------------------------------------------------------------
struct Tw {
  float2 w128a, w128b, w64;
  float2 wc[5];   // raw stage twiddles, h = 32,16,8,4,2
  float2 wf[5];   // forward per-lane post-multiplier: (l&h)? wc : (1,0)
  float  sg[5];   // (l&h) ? -1 : +1
  float  sg1;     // (l&1) ? -1 : +1
};

__device__ __forceinline__ void tw_init(Tw& t, int l){
  float s, c;
  sincosf(-TWO_PI * (float)l * (1.0f/256.0f), &s, &c);
  t.w128a = make_float2(c, s);                 // W256^l
  t.w128b = make_float2(s, -c);                // W256^(l+64)
  t.w64   = make_float2(c*c - s*s, 2.0f*c*s);  // W256^(2l)
  const int hs[5] = {32,16,8,4,2};
#pragma unroll
  for (int i = 0; i < 5; ++i){
    int h = hs[i];
    float ang = -PI_F * (float)(l & (h-1)) / (float)h;
    sincosf(ang, &s, &c);
    t.wc[i] = make_float2(c, s);
    bool dn = (l & h) != 0;
    t.wf[i] = dn ? t.wc[i] : make_float2(1.0f, 0.0f);
    t.sg[i] = dn ? -1.0f : 1.0f;
  }
  t.sg1 = (l & 1) ? -1.0f : 1.0f;
}

// forward exchange, partner-value form (ds_swizzle / DPP stages)
#define FX_OTHER(X, OTHER, SG, WF) { \
  float2 o_ = OTHER; float2 s_; \
  s_.x = fmaf(SG, X.x, o_.x); s_.y = fmaf(SG, X.y, o_.y); \
  X = cmul(WF, s_); }
// forward exchange, both-halves form (permlane stages)
#define FX_LOHI(X, SWPF, SG, WF) { \
  float2 lo_, hi_, s_; SWPF(X, lo_, hi_); \
  s_.x = fmaf(SG, hi_.x, lo_.x); s_.y = fmaf(SG, hi_.y, lo_.y); \
  X = cmul(WF, s_); }
// inverse exchange, both-halves form:  x = lo + sg * (conj(w) * hi)
#define IX_LOHI(X, SWPF, SG, WC) { \
  float2 lo_, hi_, m_; SWPF(X, lo_, hi_); \
  m_ = cmulc(WC, hi_); \
  X.x = fmaf(SG, m_.x, lo_.x); X.y = fmaf(SG, m_.y, lo_.y); }
// inverse exchange, partner form (needs role swap)
#define IX_OTHER(X, OTHER, UP, SG, WC) { \
  float2 o_ = OTHER; \
  float2 A_ = UP ? X : o_; \
  float2 B_ = UP ? o_ : X; \
  float2 m_ = cmulc(WC, B_); \
  X.x = fmaf(SG, m_.x, A_.x); X.y = fmaf(SG, m_.y, A_.y); }

__device__ __forceinline__ void fft256_fwd_padded(float2& x0, float2& x1,
                                                  float2& x2, float2& x3,
                                                  const Tw& t, int l){
  x2 = cmul(x0, t.w128a);
  x3 = cmul(x1, t.w128b);
  float2 a = x0, b = x1;
  x0 = cadd(a, b); x1 = cmul(csub(a, b), t.w64);
  a = x2; b = x3;
  x2 = cadd(a, b); x3 = cmul(csub(a, b), t.w64);
  // h = 32 : permlane32_swap (VALU)
  FX_LOHI(x0, swp32, t.sg[0], t.wf[0]);
  FX_LOHI(x1, swp32, t.sg[0], t.wf[0]);
  FX_LOHI(x2, swp32, t.sg[0], t.wf[0]);
  FX_LOHI(x3, swp32, t.sg[0], t.wf[0]);
  // h = 16 : permlane16_swap (VALU)
  FX_LOHI(x0, swp16, t.sg[1], t.wf[1]);
  FX_LOHI(x1, swp16, t.sg[1], t.wf[1]);
  FX_LOHI(x2, swp16, t.sg[1], t.wf[1]);
  FX_LOHI(x3, swp16, t.sg[1], t.wf[1]);
  // h = 8, 4 : ds_swizzle
  FX_OTHER(x0, shflx(x0, 8), t.sg[2], t.wf[2]);
  FX_OTHER(x1, shflx(x1, 8), t.sg[2], t.wf[2]);
  FX_OTHER(x2, shflx(x2, 8), t.sg[2], t.wf[2]);
  FX_OTHER(x3, shflx(x3, 8), t.sg[2], t.wf[2]);
  FX_OTHER(x0, shflx(x0, 4), t.sg[3], t.wf[3]);
  FX_OTHER(x1, shflx(x1, 4), t.sg[3], t.wf[3]);
  FX_OTHER(x2, shflx(x2, 4), t.sg[3], t.wf[3]);
  FX_OTHER(x3, shflx(x3, 4), t.sg[3], t.wf[3]);
  // h = 2 : DPP quad_perm (VALU)
  FX_OTHER(x0, dppx<DPP_XOR2>(x0), t.sg[4], t.wf[4]);
  FX_OTHER(x1, dppx<DPP_XOR2>(x1), t.sg[4], t.wf[4]);
  FX_OTHER(x2, dppx<DPP_XOR2>(x2), t.sg[4], t.wf[4]);
  FX_OTHER(x3, dppx<DPP_XOR2>(x3), t.sg[4], t.wf[4]);
  // h = 1 : DPP quad_perm, no twiddle
  {
    float2 o;
    o = dppx<DPP_XOR1>(x0); x0.x = fmaf(t.sg1, x0.x, o.x); x0.y = fmaf(t.sg1, x0.y, o.y);
    o = dppx<DPP_XOR1>(x1); x1.x = fmaf(t.sg1, x1.x, o.x); x1.y = fmaf(t.sg1, x1.y, o.y);
    o = dppx<DPP_XOR1>(x2); x2.x = fmaf(t.sg1, x2.x, o.x); x2.y = fmaf(t.sg1, x2.y, o.y);
    o = dppx<DPP_XOR1>(x3); x3.x = fmaf(t.sg1, x3.x, o.x); x3.y = fmaf(t.sg1, x3.y, o.y);
  }
}

__device__ __forceinline__ void fft256_inv_crop(float2& x0, float2& x1,
                                                float2& x2, float2& x3,
                                                const Tw& t, int l){
  // h = 1 : DPP, no twiddle
  {
    float2 o;
    o = dppx<DPP_XOR1>(x0); x0.x = fmaf(t.sg1, x0.x, o.x); x0.y = fmaf(t.sg1, x0.y, o.y);
    o = dppx<DPP_XOR1>(x1); x1.x = fmaf(t.sg1, x1.x, o.x); x1.y = fmaf(t.sg1, x1.y, o.y);
    o = dppx<DPP_XOR1>(x2); x2.x = fmaf(t.sg1, x2.x, o.x); x2.y = fmaf(t.sg1, x2.y, o.y);
    o = dppx<DPP_XOR1>(x3); x3.x = fmaf(t.sg1, x3.x, o.x); x3.y = fmaf(t.sg1, x3.y, o.y);
  }
  // h = 2 : DPP
  {
    bool up = (l & 2) == 0;
    IX_OTHER(x0, dppx<DPP_XOR2>(x0), up, t.sg[4], t.wc[4]);
    IX_OTHER(x1, dppx<DPP_XOR2>(x1), up, t.sg[4], t.wc[4]);
    IX_OTHER(x2, dppx<DPP_XOR2>(x2), up, t.sg[4], t.wc[4]);
    IX_OTHER(x3, dppx<DPP_XOR2>(x3), up, t.sg[4], t.wc[4]);
  }
  // h = 4, 8 : ds_swizzle
  {
    bool up = (l & 4) == 0;
    IX_OTHER(x0, shflx(x0, 4), up, t.sg[3], t.wc[3]);
    IX_OTHER(x1, shflx(x1, 4), up, t.sg[3], t.wc[3]);
    IX_OTHER(x2, shflx(x2, 4), up, t.sg[3], t.wc[3]);
    IX_OTHER(x3, shflx(x3, 4), up, t.sg[3], t.wc[3]);
  }
  {
    bool up = (l & 8) == 0;
    IX_OTHER(x0, shflx(x0, 8), up, t.sg[2], t.wc[2]);
    IX_OTHER(x1, shflx(x1, 8), up, t.sg[2], t.wc[2]);
    IX_OTHER(x2, shflx(x2, 8), up, t.sg[2], t.wc[2]);
    IX_OTHER(x3, shflx(x3, 8), up, t.sg[2], t.wc[2]);
  }
  // h = 16 : permlane16_swap
  IX_LOHI(x0, swp16, t.sg[1], t.wc[1]);
  IX_LOHI(x1, swp16, t.sg[1], t.wc[1]);
  IX_LOHI(x2, swp16, t.sg[1], t.wc[1]);
  IX_LOHI(x3, swp16, t.sg[1], t.wc[1]);
  // h = 32 : permlane32_swap
  IX_LOHI(x0, swp32, t.sg[0], t.wc[0]);
  IX_LOHI(x1, swp32, t.sg[0], t.wc[0]);
  IX_LOHI(x2, swp32, t.sg[0], t.wc[0]);
  IX_LOHI(x3, swp32, t.sg[0], t.wc[0]);
  {
    float2 w = make_float2(t.w64.x, -t.w64.y);
    float2 t0 = cmul(w, x1); x1 = csub(x0, t0); x0 = cadd(x0, t0);
    float2 t1 = cmul(w, x3); x3 = csub(x2, t1); x2 = cadd(x2, t1);
  }
  {
    float2 wa = make_float2(t.w128a.x, -t.w128a.y);
    float2 wb = make_float2(t.w128b.x, -t.w128b.y);
    x0 = cadd(x0, cmul(wa, x2));
    x1 = cadd(x1, cmul(wb, x3));
  }
}

// ---------------------------------------------------------------------------
// Conjugate-partner map (bin U+k, U = 4*br6(l)):
//   k=0 -> lane p0 = br6((64-r6)&63), reg x0
//   k=1 (reg x2) -> lane l^63, reg x3
//   k=2 (reg x1) -> lane l^63, reg x1
//   k=3 (reg x3) -> lane l^63, reg x2
// ---------------------------------------------------------------------------

// ---------------------------------------------------------------------------
// kprep_col: grid CC*2. Packed real-pair column FFTs of the MLP kernel
// (scaled 0.25 = both packings' 1/2), natural-bin spectrum to LDS, coalesced
// write to Khat front half.
// ---------------------------------------------------------------------------
__global__ __launch_bounds__(512) void kprep_col(const float* __restrict__ W1,
                                                 const float* __restrict__ b1,
                                                 const float* __restrict__ W2,
                                                 const float* __restrict__ b2,
                                                 float2* __restrict__ Khat){
  __shared__ float sRe[NF*65];
  __shared__ float sIm[NF*65];
  const int S = 65;
  int t = threadIdx.x, l = t & 63, w = t >> 6;
  int c  = blockIdx.x >> 1;
  int q0B = (blockIdx.x & 1) * 64;
  Tw tw; tw_init(tw, l);
  int r6 = __brev((unsigned)l) >> 26;
  int l63 = l ^ 63;
  int p0 = __brev((unsigned)((64 - r6) & 63)) >> 26;

  float w1y[16], w1x[16], bb1[16], w2r[16];
#pragma unroll
  for (int h = 0; h < 16; ++h){
    w1y[h] = W1[h]; w1x[h] = W1[16+h]; bb1[h] = b1[h];
    w2r[h] = W2[h*CC + c] * 0.25f;
  }
  float bb2 = b2[c] * 0.25f;
  float gy0 = (float)l        * (1.0f/127.0f);
  float gy1 = (float)(l + 64) * (1.0f/127.0f);

#define SEPST32(Z, P, ROW) { \
  sRe[(ROW)*S + qa] = Z.x + P.x; sIm[(ROW)*S + qa] = Z.y - P.y; \
  sRe[(ROW)*S + qb] = Z.y + P.y; sIm[(ROW)*S + qb] = P.x - Z.x; }

  for (int ji = 0; ji < 4; ++ji){
    int jj = w*4 + ji;
    int qa = 2*jj, qb = 2*jj + 1;
    float gxa = (float)(q0B + qa) * (1.0f/127.0f);
    float gxb = (float)(q0B + qb) * (1.0f/127.0f);
    float a0 = bb2, a1 = bb2, bq0 = bb2, bq1 = bb2;
#pragma unroll
    for (int h = 0; h < 16; ++h){
      float hxa = gxa*w1x[h] + bb1[h];
      float hxb = gxb*w1x[h] + bb1[h];
      a0  += fmaxf(gy0*w1y[h] + hxa, 0.0f) * w2r[h];
      a1  += fmaxf(gy1*w1y[h] + hxa, 0.0f) * w2r[h];
      bq0 += fmaxf(gy0*w1y[h] + hxb, 0.0f) * w2r[h];
      bq1 += fmaxf(gy1*w1y[h] + hxb, 0.0f) * w2r[h];
    }
    float2 x0 = make_float2(a0, bq0);
    float2 x1 = make_float2(a1, bq1);
    float2 x2, x3;
    fft256_fwd_padded(x0, x1, x2, x3, tw, l);
    float2 f0p = shfli(x0, p0);
    float2 f2p = shfli(x3, l63);
    float2 f1p = shfli(x1, l63);
    float2 f3p = shfli(x2, l63);
    if (r6 <= 32){ SEPST32(x0, f0p, 4*r6); }
    if (r6 <= 31){
      SEPST32(x2, f2p, 4*r6+1);
      SEPST32(x1, f1p, 4*r6+2);
      SEPST32(x3, f3p, 4*r6+3);
    }
  }
#undef SEPST32
  __syncthreads();
  for (int idx = t; idx < NF*64; idx += 512){
    int u = idx >> 6, qq = idx & 63;
    Khat[((size_t)c*NF + u)*FN + q0B + qq] = make_float2(sRe[u*S+qq], sIm[u*S+qq]);
  }
}

// ---------------------------------------------------------------------------
// kprep_row: grid CC*4. Register-only in-place row FFTs on Khat rows.
// ---------------------------------------------------------------------------
__global__ __launch_bounds__(512) void kprep_row(float2* __restrict__ Khat){
  int t = threadIdx.x, l = t & 63, w = t >> 6;
  int c = blockIdx.x >> 2, part = blockIdx.x & 3;
  Tw tw; tw_init(tw, l);
  for (int j = w; ; j += 8){
    int u = part + 4*j;
    if (u >= NF) break;
    float2* kp = Khat + ((size_t)c*NF + u)*FN;
    float2 x0 = kp[l], x1 = kp[64 + l], x2, x3;
    fft256_fwd_padded(x0, x1, x2, x3, tw, l);
    kp[l] = x0; kp[64 + l] = x1; kp[128 + l] = x2; kp[192 + l] = x3;
  }
}

// ---------------------------------------------------------------------------
// fused_conv: one block per (b,c) image. Whole 2D FFT-conv in LDS.
// Single interleaved u32 LDS plane with ODD word stride S=129 (bank spread
// 1 mod 32 for column-phase access — the R4 regression was S=130 even).
// All paired accesses are explicit u32 pairs (-> ds_read2/write2_b32,
// 4B-aligned OK; uint2/b64 would be misaligned at odd rows).
//   - x / y phases: PL[p][q] = raw fp32 bits (exact)
//   - spectra phases: PL[row][q] = half2 (re lo16, im hi16), cmap rows
// Step 3 packs the exactly-real rows u=0 and u=128 into one complex FFT
// -> 16 perfectly balanced row-conv tasks per wave.
// ---------------------------------------------------------------------------
__global__ __launch_bounds__(512) void fused_conv(const float* __restrict__ x,
                                                  const float2* __restrict__ Khat,
                                                  float* __restrict__ out){
  __shared__ unsigned int PL[131*129];
  const int S = 129;
  int t = threadIdx.x, l = t & 63, w = t >> 6;
  int blk = blockIdx.x;
  int c = blk >> 4, b = blk & 15;        // 16 consecutive blocks share c (Khat L2 reuse)
  const float* xp = x   + ((size_t)b*CC + c)*(HH*WW);
  float*       yp = out + ((size_t)b*CC + c)*(HH*WW);
  Tw tw; tw_init(tw, l);
  int r6 = __brev((unsigned)l) >> 26;
  int l63 = l ^ 63;
  int p0 = __brev((unsigned)((64 - r6) & 63)) >> 26;

  // 1) x -> raw fp32 bits
  for (int i = t; i < HH*WW; i += 512){
    int p = i >> 7, q = i & 127;
    PL[p*S + q] = __float_as_uint(xp[i]);
  }
  __syncthreads();
  // 2) packed column forward FFTs (cols 2j,2j+1); separate; store half2 bins
#define SEPST16(Z, P, ROW) { \
  PL[(ROW)*S + q0]     = pkh2(Z.x + P.x, Z.y - P.y); \
  PL[(ROW)*S + q0 + 1] = pkh2(Z.y + P.y, P.x - Z.x); }

  for (int ji = 0; ji < 8; ++ji){
    int jj = w*8 + ji;                     // pair index 0..63
    int q0 = 2*jj;
    unsigned v0a = PL[l*S + q0],        v0b = PL[l*S + q0 + 1];
    unsigned v1a = PL[(l+64)*S + q0],   v1b = PL[(l+64)*S + q0 + 1];
    float2 x0 = make_float2(__uint_as_float(v0a), __uint_as_float(v0b));
    float2 x1 = make_float2(__uint_as_float(v1a), __uint_as_float(v1b));
    float2 x2, x3;
    fft256_fwd_padded(x0, x1, x2, x3, tw, l);
    float2 f0p = shfli(x0, p0);
    float2 f2p = shfli(x3, l63);
    float2 f1p = shfli(x1, l63);
    float2 f3p = shfli(x2, l63);
    if (r6 <= 32){ SEPST16(x0, f0p, r6); }          // bin 4r6    -> row r6
    if (r6 <= 31){
      SEPST16(x2, f2p, 33+r6);                      // bin 4r6+1
      SEPST16(x1, f1p, 66+r6);                      // bin 4r6+2
      SEPST16(x3, f3p, 99+r6);                      // bin 4r6+3
    }
  }
#undef SEPST16
  __syncthreads();
  // 3) row conv, 16 balanced tasks/wave. Wave 0 task 0 = packed rows (0,128).
  for (int k = 0; k < 16; ++k){
    int u = w + 8*k;
    if (w == 0 && k == 0){
      // -------- packed real rows u=0 (pr=0) and u=128 (pr=32) --------
      unsigned a0 = PL[l],           a1 = PL[64 + l];        // row 0
      unsigned c0 = PL[32*S + l],    c1 = PL[32*S + 64 + l]; // row 32
      float2 x0 = make_float2(h2lo(a0), h2lo(c0));
      float2 x1 = make_float2(h2lo(a1), h2lo(c1));
      float2 x2, x3;
      fft256_fwd_padded(x0, x1, x2, x3, tw, l);
      float2 f0p = shfli(x0, p0);
      float2 f2p = shfli(x3, l63);
      float2 f1p = shfli(x1, l63);
      float2 f3p = shfli(x2, l63);
      const float2* k0p = Khat + (size_t)c*NF*FN;        // u = 0
      const float2* k1p = k0p + (size_t)128*FN;          // u = 128
#define PKMUL(Z, P, OFF) { \
      float2 A2_ = make_float2(Z.x + P.x, Z.y - P.y); \
      float2 B2_ = make_float2(Z.y + P.y, P.x - Z.x); \
      float2 m0_ = cmul(A2_, k0p[OFF]); \
      float2 m1_ = cmul(B2_, k1p[OFF]); \
      Z = make_float2(m0_.x - m1_.y, m0_.y + m1_.x); }
      PKMUL(x0, f0p, l);
      PKMUL(x2, f2p, 128 + l);
      PKMUL(x1, f1p, 64 + l);
      PKMUL(x3, f3p, 192 + l);
#undef PKMUL
      fft256_inv_crop(x0, x1, x2, x3, tw, l);
      const float sc = SCL_DN * 0.5f;      // extra 1/2 from this packing
      PL[l]           = pkh2(x0.x * sc, 0.0f);   // Y[0][l]   (real)
      PL[32*S + l]    = pkh2(x0.y * sc, 0.0f);   // Y[128][l] (real)
      PL[64 + l]      = pkh2(x1.x * sc, 0.0f);
      PL[32*S + 64+l] = pkh2(x1.y * sc, 0.0f);
    } else {
      int pr = (u >> 2) + 33*(u & 3);
      unsigned ua = PL[pr*S + l];
      unsigned ub = PL[pr*S + 64 + l];
      float2 x0 = make_float2(h2lo(ua), h2hi(ua));
      float2 x1 = make_float2(h2lo(ub), h2hi(ub));
      float2 x2, x3;
      fft256_fwd_padded(x0, x1, x2, x3, tw, l);
      const float2* kp = Khat + ((size_t)c*NF + u)*FN;
      x0 = cmul(x0, kp[l]);
      x1 = cmul(x1, kp[64 + l]);
      x2 = cmul(x2, kp[128 + l]);
      x3 = cmul(x3, kp[192 + l]);
      fft256_inv_crop(x0, x1, x2, x3, tw, l);
      PL[pr*S + l]      = pkh2(x0.x * SCL_DN, x0.y * SCL_DN);
      PL[pr*S + 64 + l] = pkh2(x1.x * SCL_DN, x1.y * SCL_DN);
    }
  }
  __syncthreads();
  // 4) packed column inverse (Hermitian gather by natural bin) + crop -> y bits
#define GATHV(X, ROWA, ROWB, COND) { \
  int row_ = (COND) ? (ROWA) : (ROWB); \
  float s_ = (COND) ? -1.0f : 1.0f; \
  unsigned ux_ = PL[row_*S + q0]; \
  unsigned uy_ = PL[row_*S + q0 + 1]; \
  X = make_float2(fmaf(s_, h2hi(uy_), h2lo(ux_)), \
                  fmaf(-s_, h2hi(ux_), h2lo(uy_))); }

  for (int ji = 0; ji < 8; ++ji){
    int jj = w*8 + ji;
    int q0 = 2*jj;
    float2 x0, x1, x2, x3;
    GATHV(x0, r6,    64-r6,  r6 <= 32);    // bins 4r6
    GATHV(x2, 33+r6, 162-r6, r6 <= 31);    // bins 4r6+1
    GATHV(x1, 66+r6, 129-r6, r6 <= 31);    // bins 4r6+2
    GATHV(x3, 99+r6, 96-r6,  r6 <= 31);    // bins 4r6+3
    fft256_inv_crop(x0, x1, x2, x3, tw, l);
    PL[l*S + q0]          = __float_as_uint(x0.x * SCL_UP);
    PL[l*S + q0 + 1]      = __float_as_uint(x0.y * SCL_UP);
    PL[(l+64)*S + q0]     = __float_as_uint(x1.x * SCL_UP);
    PL[(l+64)*S + q0 + 1] = __float_as_uint(x1.y * SCL_UP);
  }
#undef GATHV
  __syncthreads();
  // 5) out = y + x (coalesced)
  for (int i = t; i < HH*WW; i += 512){
    int p = i >> 7, q = i & 127;
    yp[i] = __uint_as_float(PL[p*S + q]) + xp[i];
  }
}

// ---------------------------------------------------------------------------
// Host launcher
// ---------------------------------------------------------------------------
extern "C" void kernel_launch(void* const* d_in, const int* in_sizes, int n_in,
                              void* d_out, int out_size, void* d_ws, size_t ws_size,
                              hipStream_t stream) {
  const float* x  = (const float*)d_in[0];
  const float* W1 = (const float*)d_in[1];
  const float* b1 = (const float*)d_in[2];
  const float* W2 = (const float*)d_in[3];
  const float* b2 = (const float*)d_in[4];
  float* out = (float*)d_out;

  float2* Khat = (float2*)d_ws;   // CC*NF*FN complex = 25.4 MB

  kprep_col<<<CC*2, 512, 0, stream>>>(W1, b1, W2, b2, Khat);
  kprep_row<<<CC*4, 512, 0, stream>>>(Khat);
  fused_conv<<<CC*BB, 512, 0, stream>>>(x, Khat, out);
}

// Round 8
// 376.867 us; speedup vs baseline: 1.8128x; 1.1135x over previous
//
#include <hip/hip_runtime.h>
#include <hip/hip_fp16.h>

#define TWO_PI 6.283185307179586f
#define PI_F   3.14159265358979f

// Problem constants
#define HH 128      // H
#define WW 128      // W
#define FN 256      // padded FFT size (2H)
#define NF 129      // FN/2+1 vertical frequency bins
#define CC 96
#define BB 16

#define SCL_DN 0.0009765625f   // 2^-10 : folded into Khat fp16 storage
#define SCL_UP 1024.0f

typedef unsigned int uint2v __attribute__((ext_vector_type(2)));
typedef __fp16 half2v __attribute__((ext_vector_type(2)));

__device__ __forceinline__ float2 cmul(float2 a, float2 b){
  return make_float2(a.x*b.x - a.y*b.y, a.x*b.y + a.y*b.x);
}
__device__ __forceinline__ float2 cmulc(float2 a, float2 b){   // conj(a)*b
  return make_float2(a.x*b.x + a.y*b.y, a.x*b.y - a.y*b.x);
}
__device__ __forceinline__ float2 cadd(float2 a, float2 b){ return make_float2(a.x+b.x, a.y+b.y); }
__device__ __forceinline__ float2 csub(float2 a, float2 b){ return make_float2(a.x-b.x, a.y-b.y); }
__device__ __forceinline__ float2 shflx(float2 v, int m){
  float2 r; r.x = __shfl_xor(v.x, m, 64); r.y = __shfl_xor(v.y, m, 64); return r;
}
__device__ __forceinline__ float2 shfli(float2 v, int idx){
  float2 r; r.x = __shfl(v.x, idx, 64); r.y = __shfl(v.y, idx, 64); return r;
}
__device__ __forceinline__ unsigned short f2h(float v){ return __half_as_ushort(__float2half(v)); }
__device__ __forceinline__ float h2f(unsigned short u){ return __half2float(__ushort_as_half(u)); }
__device__ __forceinline__ unsigned pkh2(float a, float b){
  union { half2v h; unsigned u; } cv;
  cv.h = __builtin_amdgcn_cvt_pkrtz(a, b);     // v_cvt_pkrtz_f16_f32: lo=a, hi=b
  return cv.u;
}
__device__ __forceinline__ float h2lo(unsigned u){ return h2f((unsigned short)(u & 0xffffu)); }
__device__ __forceinline__ float h2hi(unsigned u){ return h2f((unsigned short)(u >> 16)); }

// half2 bit helpers
__device__ __forceinline__ unsigned h22u(__half2 h){ union{__half2 h; unsigned u;} c; c.h=h; return c.u; }
__device__ __forceinline__ __half2 u2h2(unsigned u){ union{unsigned u; __half2 h;} c; c.u=u; return c.h; }
__device__ __forceinline__ __half2 pk2h(float a, float b){ return u2h2(pkh2(a,b)); }
__device__ __forceinline__ __half2 swap_h2(__half2 a){
  unsigned u = h22u(a); return u2h2((u >> 16) | (u << 16));   // v_alignbit
}
// packed complex multiply: s * w, with w pre-split as wrr=(c,c), wdd=(-d,d).
// For conj(w)*s use wdd=(d,-d).
__device__ __forceinline__ __half2 cmulW_h2(__half2 s, __half2 wrr, __half2 wdd){
  return __hfma2(swap_h2(s), wdd, __hmul2(s, wrr));
}

// ---------------------------------------------------------------------------
// Cross-lane helpers (f32 path): permlane swaps + DPP quad_perm.
// ---------------------------------------------------------------------------
__device__ __forceinline__ void swp32(float2 v, float2& lo, float2& hi){
  uint2v rx = __builtin_amdgcn_permlane32_swap(__float_as_uint(v.x), __float_as_uint(v.x), false, false);
  uint2v ry = __builtin_amdgcn_permlane32_swap(__float_as_uint(v.y), __float_as_uint(v.y), false, false);
  lo = make_float2(__uint_as_float(rx[0]), __uint_as_float(ry[0]));
  hi = make_float2(__uint_as_float(rx[1]), __uint_as_float(ry[1]));
}
__device__ __forceinline__ void swp16(float2 v, float2& lo, float2& hi){
  uint2v rx = __builtin_amdgcn_permlane16_swap(__float_as_uint(v.x), __float_as_uint(v.x), false, false);
  uint2v ry = __builtin_amdgcn_permlane16_swap(__float_as_uint(v.y), __float_as_uint(v.y), false, false);
  lo = make_float2(__uint_as_float(rx[0]), __uint_as_float(ry[0]));
  hi = make_float2(__uint_as_float(rx[1]), __uint_as_float(ry[1]));
}
template<int CTRL>
__device__ __forceinline__ float2 dppx(float2 v){
  float2 r;
  r.x = __uint_as_float((unsigned)__builtin_amdgcn_update_dpp(0, (int)__float_as_uint(v.x), CTRL, 0xF, 0xF, true));
  r.y = __uint_as_float((unsigned)__builtin_amdgcn_update_dpp(0, (int)__float_as_uint(v.y), CTRL, 0xF, 0xF, true));
  return r;
}
template<int CTRL>
__device__ __forceinline__ unsigned dppu(unsigned v){
  return (unsigned)__builtin_amdgcn_update_dpp(0, (int)v, CTRL, 0xF, 0xF, true);
}
#define DPP_XOR1 0xB1   // quad_perm [1,0,3,2]
#define DPP_XOR2 0x4E   // quad_perm [2,3,0,1]

// ---------------------------------------------------------------------------
// f32 wave-resident 256-pt FFT (steps 2/4 + kprep). Lane l holds positions
// l, l+64, l+128, l+192. DIF out: lane l holds bins 4*br6(l)+{0,1,2,3} in
// regs (x0,x2,x1,x3). Select-free butterflies (per-lane sigma/twiddle).
// ---------------------------------------------------------------------------
struct Tw {
  float2 w128a, w128b, w64;
  float2 wc[5];
  float2 wf[5];
  float  sg[5];
  float  sg1;
};

__device__ __forceinline__ void tw_init(Tw& t, int l){
  float s, c;
  sincosf(-TWO_PI * (float)l * (1.0f/256.0f), &s, &c);
  t.w128a = make_float2(c, s);
  t.w128b = make_float2(s, -c);
  t.w64   = make_float2(c*c - s*s, 2.0f*c*s);
  const int hs[5] = {32,16,8,4,2};
#pragma unroll
  for (int i = 0; i < 5; ++i){
    int h = hs[i];
    float ang = -PI_F * (float)(l & (h-1)) / (float)h;
    sincosf(ang, &s, &c);
    t.wc[i] = make_float2(c, s);
    bool dn = (l & h) != 0;
    t.wf[i] = dn ? t.wc[i] : make_float2(1.0f, 0.0f);
    t.sg[i] = dn ? -1.0f : 1.0f;
  }
  t.sg1 = (l & 1) ? -1.0f : 1.0f;
}

#define FX_OTHER(X, OTHER, SG, WF) { \
  float2 o_ = OTHER; float2 s_; \
  s_.x = fmaf(SG, X.x, o_.x); s_.y = fmaf(SG, X.y, o_.y); \
  X = cmul(WF, s_); }
#define FX_LOHI(X, SWPF, SG, WF) { \
  float2 lo_, hi_, s_; SWPF(X, lo_, hi_); \
  s_.x = fmaf(SG, hi_.x, lo_.x); s_.y = fmaf(SG, hi_.y, lo_.y); \
  X = cmul(WF, s_); }
#define IX_LOHI(X, SWPF, SG, WC) { \
  float2 lo_, hi_, m_; SWPF(X, lo_, hi_); \
  m_ = cmulc(WC, hi_); \
  X.x = fmaf(SG, m_.x, lo_.x); X.y = fmaf(SG, m_.y, lo_.y); }
#define IX_OTHER(X, OTHER, UP, SG, WC) { \
  float2 o_ = OTHER; \
  float2 A_ = UP ? X : o_; \
  float2 B_ = UP ? o_ : X; \
  float2 m_ = cmulc(WC, B_); \
  X.x = fmaf(SG, m_.x, A_.x); X.y = fmaf(SG, m_.y, A_.y); }

__device__ __forceinline__ void fft256_fwd_padded(float2& x0, float2& x1,
                                                  float2& x2, float2& x3,
                                                  const Tw& t, int l){
  x2 = cmul(x0, t.w128a);
  x3 = cmul(x1, t.w128b);
  float2 a = x0, b = x1;
  x0 = cadd(a, b); x1 = cmul(csub(a, b), t.w64);
  a = x2; b = x3;
  x2 = cadd(a, b); x3 = cmul(csub(a, b), t.w64);
  FX_LOHI(x0, swp32, t.sg[0], t.wf[0]);
  FX_LOHI(x1, swp32, t.sg[0], t.wf[0]);
  FX_LOHI(x2, swp32, t.sg[0], t.wf[0]);
  FX_LOHI(x3, swp32, t.sg[0], t.wf[0]);
  FX_LOHI(x0, swp16, t.sg[1], t.wf[1]);
  FX_LOHI(x1, swp16, t.sg[1], t.wf[1]);
  FX_LOHI(x2, swp16, t.sg[1], t.wf[1]);
  FX_LOHI(x3, swp16, t.sg[1], t.wf[1]);
  FX_OTHER(x0, shflx(x0, 8), t.sg[2], t.wf[2]);
  FX_OTHER(x1, shflx(x1, 8), t.sg[2], t.wf[2]);
  FX_OTHER(x2, shflx(x2, 8), t.sg[2], t.wf[2]);
  FX_OTHER(x3, shflx(x3, 8), t.sg[2], t.wf[2]);
  FX_OTHER(x0, shflx(x0, 4), t.sg[3], t.wf[3]);
  FX_OTHER(x1, shflx(x1, 4), t.sg[3], t.wf[3]);
  FX_OTHER(x2, shflx(x2, 4), t.sg[3], t.wf[3]);
  FX_OTHER(x3, shflx(x3, 4), t.sg[3], t.wf[3]);
  FX_OTHER(x0, dppx<DPP_XOR2>(x0), t.sg[4], t.wf[4]);
  FX_OTHER(x1, dppx<DPP_XOR2>(x1), t.sg[4], t.wf[4]);
  FX_OTHER(x2, dppx<DPP_XOR2>(x2), t.sg[4], t.wf[4]);
  FX_OTHER(x3, dppx<DPP_XOR2>(x3), t.sg[4], t.wf[4]);
  {
    float2 o;
    o = dppx<DPP_XOR1>(x0); x0.x = fmaf(t.sg1, x0.x, o.x); x0.y = fmaf(t.sg1, x0.y, o.y);
    o = dppx<DPP_XOR1>(x1); x1.x = fmaf(t.sg1, x1.x, o.x); x1.y = fmaf(t.sg1, x1.y, o.y);
    o = dppx<DPP_XOR1>(x2); x2.x = fmaf(t.sg1, x2.x, o.x); x2.y = fmaf(t.sg1, x2.y, o.y);
    o = dppx<DPP_XOR1>(x3); x3.x = fmaf(t.sg1, x3.x, o.x); x3.y = fmaf(t.sg1, x3.y, o.y);
  }
}

__device__ __forceinline__ void fft256_inv_crop(float2& x0, float2& x1,
                                                float2& x2, float2& x3,
                                                const Tw& t, int l){
  {
    float2 o;
    o = dppx<DPP_XOR1>(x0); x0.x = fmaf(t.sg1, x0.x, o.x); x0.y = fmaf(t.sg1, x0.y, o.y);
    o = dppx<DPP_XOR1>(x1); x1.x = fmaf(t.sg1, x1.x, o.x); x1.y = fmaf(t.sg1, x1.y, o.y);
    o = dppx<DPP_XOR1>(x2); x2.x = fmaf(t.sg1, x2.x, o.x); x2.y = fmaf(t.sg1, x2.y, o.y);
    o = dppx<DPP_XOR1>(x3); x3.x = fmaf(t.sg1, x3.x, o.x); x3.y = fmaf(t.sg1, x3.y, o.y);
  }
  {
    bool up = (l & 2) == 0;
    IX_OTHER(x0, dppx<DPP_XOR2>(x0), up, t.sg[4], t.wc[4]);
    IX_OTHER(x1, dppx<DPP_XOR2>(x1), up, t.sg[4], t.wc[4]);
    IX_OTHER(x2, dppx<DPP_XOR2>(x2), up, t.sg[4], t.wc[4]);
    IX_OTHER(x3, dppx<DPP_XOR2>(x3), up, t.sg[4], t.wc[4]);
  }
  {
    bool up = (l & 4) == 0;
    IX_OTHER(x0, shflx(x0, 4), up, t.sg[3], t.wc[3]);
    IX_OTHER(x1, shflx(x1, 4), up, t.sg[3], t.wc[3]);
    IX_OTHER(x2, shflx(x2, 4), up, t.sg[3], t.wc[3]);
    IX_OTHER(x3, shflx(x3, 4), up, t.sg[3], t.wc[3]);
  }
  {
    bool up = (l & 8) == 0;
    IX_OTHER(x0, shflx(x0, 8), up, t.sg[2], t.wc[2]);
    IX_OTHER(x1, shflx(x1, 8), up, t.sg[2], t.wc[2]);
    IX_OTHER(x2, shflx(x2, 8), up, t.sg[2], t.wc[2]);
    IX_OTHER(x3, shflx(x3, 8), up, t.sg[2], t.wc[2]);
  }
  IX_LOHI(x0, swp16, t.sg[1], t.wc[1]);
  IX_LOHI(x1, swp16, t.sg[1], t.wc[1]);
  IX_LOHI(x2, swp16, t.sg[1], t.wc[1]);
  IX_LOHI(x3, swp16, t.sg[1], t.wc[1]);
  IX_LOHI(x0, swp32, t.sg[0], t.wc[0]);
  IX_LOHI(x1, swp32, t.sg[0], t.wc[0]);
  IX_LOHI(x2, swp32, t.sg[0], t.wc[0]);
  IX_LOHI(x3, swp32, t.sg[0], t.wc[0]);
  {
    float2 w = make_float2(t.w64.x, -t.w64.y);
    float2 t0 = cmul(w, x1); x1 = csub(x0, t0); x0 = cadd(x0, t0);
    float2 t1 = cmul(w, x3); x3 = csub(x2, t1); x2 = cadd(x2, t1);
  }
  {
    float2 wa = make_float2(t.w128a.x, -t.w128a.y);
    float2 wb = make_float2(t.w128b.x, -t.w128b.y);
    x0 = cadd(x0, cmul(wa, x2));
    x1 = cadd(x1, cmul(wb, x3));
  }
}

// ---------------------------------------------------------------------------
// Packed-fp16 256-pt FFT for step 3 (row conv). Same dataflow as the f32
// version; one complex value = one u32 half2 = one VGPR. Twiddles pre-split
// (wrr, wdd) so each cmul is alignbit + pk_mul + pk_fma.
// ---------------------------------------------------------------------------
struct Tw2 {
  __half2 war, wad, wbr, wbd, w64r, w64d;           // forward entry
  __half2 wfr[5], wfd[5];                           // forward stage
  __half2 wcr[5], wcdc[5];                          // inverse stage (conj)
  __half2 sg2[5], sg12;
  __half2 w64cr, w64cdc, wacr, wacdc, wbcr, wbcdc;  // inverse tail
};

__device__ __forceinline__ void tw2_init(Tw2& t, int l){
  float s, c;
  sincosf(-TWO_PI * (float)l * (1.0f/256.0f), &s, &c);
  float c2 = c*c - s*s, s2 = 2.0f*c*s;
  t.war  = pk2h(c, c);    t.wad   = pk2h(-s, s);
  t.wbr  = pk2h(s, s);    t.wbd   = pk2h(c, -c);     // w128b=(s,-c): d=-c
  t.w64r = pk2h(c2, c2);  t.w64d  = pk2h(-s2, s2);
  t.wacr = pk2h(c, c);    t.wacdc = pk2h(s, -s);     // conj(w128a)
  t.wbcr = pk2h(s, s);    t.wbcdc = pk2h(-c, c);     // conj(w128b): d=-c -> (d,-d)=(-c,c)
  t.w64cr = pk2h(c2, c2); t.w64cdc = pk2h(s2, -s2);
  const int hs[5] = {32,16,8,4,2};
#pragma unroll
  for (int i = 0; i < 5; ++i){
    int h = hs[i];
    float ang = -PI_F * (float)(l & (h-1)) / (float)h;
    float si, ci; sincosf(ang, &si, &ci);
    bool dn = (l & h) != 0;
    t.wfr[i]  = dn ? pk2h(ci, ci) : pk2h(1.0f, 1.0f);
    t.wfd[i]  = dn ? pk2h(-si, si) : pk2h(0.0f, 0.0f);
    t.wcr[i]  = pk2h(ci, ci);
    t.wcdc[i] = pk2h(si, -si);
    t.sg2[i]  = dn ? pk2h(-1.0f, -1.0f) : pk2h(1.0f, 1.0f);
  }
  t.sg12 = (l & 1) ? pk2h(-1.0f, -1.0f) : pk2h(1.0f, 1.0f);
}

__device__ __forceinline__ void fft256_fwd_h2(__half2& x0, __half2& x1,
                                              __half2& x2, __half2& x3,
                                              const Tw2& t){
  x2 = cmulW_h2(x0, t.war, t.wad);
  x3 = cmulW_h2(x1, t.wbr, t.wbd);
  __half2 a = x0;
  x0 = __hadd2(a, x1);
  x1 = cmulW_h2(__hsub2(a, x1), t.w64r, t.w64d);
  a = x2;
  x2 = __hadd2(a, x3);
  x3 = cmulW_h2(__hsub2(a, x3), t.w64r, t.w64d);
#define FWD_P32(X) { unsigned u_ = h22u(X); \
  uint2v r_ = __builtin_amdgcn_permlane32_swap(u_, u_, false, false); \
  __half2 s_ = __hfma2(t.sg2[0], u2h2(r_[1]), u2h2(r_[0])); \
  X = cmulW_h2(s_, t.wfr[0], t.wfd[0]); }
  FWD_P32(x0) FWD_P32(x1) FWD_P32(x2) FWD_P32(x3)
#undef FWD_P32
#define FWD_P16(X) { unsigned u_ = h22u(X); \
  uint2v r_ = __builtin_amdgcn_permlane16_swap(u_, u_, false, false); \
  __half2 s_ = __hfma2(t.sg2[1], u2h2(r_[1]), u2h2(r_[0])); \
  X = cmulW_h2(s_, t.wfr[1], t.wfd[1]); }
  FWD_P16(x0) FWD_P16(x1) FWD_P16(x2) FWD_P16(x3)
#undef FWD_P16
#define FWD_SH(X, M, I) { unsigned o_ = (unsigned)__shfl_xor((int)h22u(X), M, 64); \
  __half2 s_ = __hfma2(t.sg2[I], X, u2h2(o_)); \
  X = cmulW_h2(s_, t.wfr[I], t.wfd[I]); }
  FWD_SH(x0, 8, 2) FWD_SH(x1, 8, 2) FWD_SH(x2, 8, 2) FWD_SH(x3, 8, 2)
  FWD_SH(x0, 4, 3) FWD_SH(x1, 4, 3) FWD_SH(x2, 4, 3) FWD_SH(x3, 4, 3)
#undef FWD_SH
#define FWD_D2(X) { unsigned o_ = dppu<DPP_XOR2>(h22u(X)); \
  __half2 s_ = __hfma2(t.sg2[4], X, u2h2(o_)); \
  X = cmulW_h2(s_, t.wfr[4], t.wfd[4]); }
  FWD_D2(x0) FWD_D2(x1) FWD_D2(x2) FWD_D2(x3)
#undef FWD_D2
#define FWD_D1(X) { unsigned o_ = dppu<DPP_XOR1>(h22u(X)); \
  X = __hfma2(t.sg12, X, u2h2(o_)); }
  FWD_D1(x0) FWD_D1(x1) FWD_D1(x2) FWD_D1(x3)
#undef FWD_D1
}

__device__ __forceinline__ void fft256_inv_h2(__half2& x0, __half2& x1,
                                              __half2& x2, __half2& x3,
                                              const Tw2& t, int l){
#define INV_D1(X) { unsigned o_ = dppu<DPP_XOR1>(h22u(X)); \
  X = __hfma2(t.sg12, X, u2h2(o_)); }
  INV_D1(x0) INV_D1(x1) INV_D1(x2) INV_D1(x3)
#undef INV_D1
  {
    bool up = (l & 2) == 0;
#define INV_D2(X) { unsigned xu_ = h22u(X); unsigned ou_ = dppu<DPP_XOR2>(xu_); \
    unsigned Au_ = up ? xu_ : ou_; unsigned Bu_ = up ? ou_ : xu_; \
    __half2 m_ = cmulW_h2(u2h2(Bu_), t.wcr[4], t.wcdc[4]); \
    X = __hfma2(t.sg2[4], m_, u2h2(Au_)); }
    INV_D2(x0) INV_D2(x1) INV_D2(x2) INV_D2(x3)
#undef INV_D2
  }
  {
    bool up = (l & 4) == 0;
#define INV_S4(X) { unsigned xu_ = h22u(X); \
    unsigned ou_ = (unsigned)__shfl_xor((int)xu_, 4, 64); \
    unsigned Au_ = up ? xu_ : ou_; unsigned Bu_ = up ? ou_ : xu_; \
    __half2 m_ = cmulW_h2(u2h2(Bu_), t.wcr[3], t.wcdc[3]); \
    X = __hfma2(t.sg2[3], m_, u2h2(Au_)); }
    INV_S4(x0) INV_S4(x1) INV_S4(x2) INV_S4(x3)
#undef INV_S4
  }
  {
    bool up = (l & 8) == 0;
#define INV_S8(X) { unsigned xu_ = h22u(X); \
    unsigned ou_ = (unsigned)__shfl_xor((int)xu_, 8, 64); \
    unsigned Au_ = up ? xu_ : ou_; unsigned Bu_ = up ? ou_ : xu_; \
    __half2 m_ = cmulW_h2(u2h2(Bu_), t.wcr[2], t.wcdc[2]); \
    X = __hfma2(t.sg2[2], m_, u2h2(Au_)); }
    INV_S8(x0) INV_S8(x1) INV_S8(x2) INV_S8(x3)
#undef INV_S8
  }
#define INV_P16(X) { unsigned u_ = h22u(X); \
  uint2v r_ = __builtin_amdgcn_permlane16_swap(u_, u_, false, false); \
  __half2 m_ = cmulW_h2(u2h2(r_[1]), t.wcr[1], t.wcdc[1]); \
  X = __hfma2(t.sg2[1], m_, u2h2(r_[0])); }
  INV_P16(x0) INV_P16(x1) INV_P16(x2) INV_P16(x3)
#undef INV_P16
#define INV_P32(X) { unsigned u_ = h22u(X); \
  uint2v r_ = __builtin_amdgcn_permlane32_swap(u_, u_, false, false); \
  __half2 m_ = cmulW_h2(u2h2(r_[1]), t.wcr[0], t.wcdc[0]); \
  X = __hfma2(t.sg2[0], m_, u2h2(r_[0])); }
  INV_P32(x0) INV_P32(x1) INV_P32(x2) INV_P32(x3)
#undef INV_P32
  {
    __half2 t0 = cmulW_h2(x1, t.w64cr, t.w64cdc);
    x1 = __hsub2(x0, t0); x0 = __hadd2(x0, t0);
    __half2 t1 = cmulW_h2(x3, t.w64cr, t.w64cdc);
    x3 = __hsub2(x2, t1); x2 = __hadd2(x2, t1);
    x0 = __hadd2(x0, cmulW_h2(x2, t.wacr, t.wacdc));
    x1 = __hadd2(x1, cmulW_h2(x3, t.wbcr, t.wbcdc));
  }
}

// ---------------------------------------------------------------------------
// kprep_col: grid CC*2. Packed real-pair column FFTs of the MLP kernel
// (scaled 0.25 = both packings' 1/2), f32 spectra to Khat front half.
// ---------------------------------------------------------------------------
__global__ __launch_bounds__(512) void kprep_col(const float* __restrict__ W1,
                                                 const float* __restrict__ b1,
                                                 const float* __restrict__ W2,
                                                 const float* __restrict__ b2,
                                                 float2* __restrict__ Khat){
  __shared__ float sRe[NF*65];
  __shared__ float sIm[NF*65];
  const int S = 65;
  int t = threadIdx.x, l = t & 63, w = t >> 6;
  int c  = blockIdx.x >> 1;
  int q0B = (blockIdx.x & 1) * 64;
  Tw tw; tw_init(tw, l);
  int r6 = __brev((unsigned)l) >> 26;
  int l63 = l ^ 63;
  int p0 = __brev((unsigned)((64 - r6) & 63)) >> 26;

  float w1y[16], w1x[16], bb1[16], w2r[16];
#pragma unroll
  for (int h = 0; h < 16; ++h){
    w1y[h] = W1[h]; w1x[h] = W1[16+h]; bb1[h] = b1[h];
    w2r[h] = W2[h*CC + c] * 0.25f;
  }
  float bb2 = b2[c] * 0.25f;
  float gy0 = (float)l        * (1.0f/127.0f);
  float gy1 = (float)(l + 64) * (1.0f/127.0f);

#define SEPST32(Z, P, ROW) { \
  sRe[(ROW)*S + qa] = Z.x + P.x; sIm[(ROW)*S + qa] = Z.y - P.y; \
  sRe[(ROW)*S + qb] = Z.y + P.y; sIm[(ROW)*S + qb] = P.x - Z.x; }

  for (int ji = 0; ji < 4; ++ji){
    int jj = w*4 + ji;
    int qa = 2*jj, qb = 2*jj + 1;
    float gxa = (float)(q0B + qa) * (1.0f/127.0f);
    float gxb = (float)(q0B + qb) * (1.0f/127.0f);
    float a0 = bb2, a1 = bb2, bq0 = bb2, bq1 = bb2;
#pragma unroll
    for (int h = 0; h < 16; ++h){
      float hxa = gxa*w1x[h] + bb1[h];
      float hxb = gxb*w1x[h] + bb1[h];
      a0  += fmaxf(gy0*w1y[h] + hxa, 0.0f) * w2r[h];
      a1  += fmaxf(gy1*w1y[h] + hxa, 0.0f) * w2r[h];
      bq0 += fmaxf(gy0*w1y[h] + hxb, 0.0f) * w2r[h];
      bq1 += fmaxf(gy1*w1y[h] + hxb, 0.0f) * w2r[h];
    }
    float2 x0 = make_float2(a0, bq0);
    float2 x1 = make_float2(a1, bq1);
    float2 x2, x3;
    fft256_fwd_padded(x0, x1, x2, x3, tw, l);
    float2 f0p = shfli(x0, p0);
    float2 f2p = shfli(x3, l63);
    float2 f1p = shfli(x1, l63);
    float2 f3p = shfli(x2, l63);
    if (r6 <= 32){ SEPST32(x0, f0p, 4*r6); }
    if (r6 <= 31){
      SEPST32(x2, f2p, 4*r6+1);
      SEPST32(x1, f1p, 4*r6+2);
      SEPST32(x3, f3p, 4*r6+3);
    }
  }
#undef SEPST32
  __syncthreads();
  for (int idx = t; idx < NF*64; idx += 512){
    int u = idx >> 6, qq = idx & 63;
    Khat[((size_t)c*NF + u)*FN + q0B + qq] = make_float2(sRe[u*S+qq], sIm[u*S+qq]);
  }
}

// ---------------------------------------------------------------------------
// kprep_row: grid CC*4. In-place f32 row FFTs; stores PRE-SPLIT fp16 K with
// SCL_DN folded: per bin (krr=(Kre,Kre), kdd=(-Kim,Kim))*2^-10, one uint2
// per float2 slot (same layout/footprint).
// ---------------------------------------------------------------------------
__global__ __launch_bounds__(512) void kprep_row(float2* __restrict__ Khat){
  int t = threadIdx.x, l = t & 63, w = t >> 6;
  int c = blockIdx.x >> 2, part = blockIdx.x & 3;
  Tw tw; tw_init(tw, l);
  for (int j = w; ; j += 8){
    int u = part + 4*j;
    if (u >= NF) break;
    float2* kp = Khat + ((size_t)c*NF + u)*FN;
    float2 x0 = kp[l], x1 = kp[64 + l], x2, x3;
    fft256_fwd_padded(x0, x1, x2, x3, tw, l);
    uint2* kp2 = (uint2*)kp;
#define KST(V, X) { float re_ = X.x * SCL_DN, im_ = X.y * SCL_DN; \
    kp2[V] = make_uint2(pkh2(re_, re_), pkh2(-im_, im_)); }
    KST(l, x0); KST(64 + l, x1); KST(128 + l, x2); KST(192 + l, x3);
#undef KST
  }
}

// ---------------------------------------------------------------------------
// fused_conv: one block per (b,c) image. 2D FFT-conv in LDS.
// Single u32 plane, ODD word stride S=129 (conflict-free columns).
//   - x / y phases: raw fp32 bits (exact)
//   - spectra: half2 (re lo, im hi) per u32
// Step 3 (row conv) runs entirely in packed fp16 (v_pk_*), K pre-split.
// ---------------------------------------------------------------------------
__global__ __launch_bounds__(512) void fused_conv(const float* __restrict__ x,
                                                  const float2* __restrict__ Khat,
                                                  float* __restrict__ out){
  __shared__ unsigned int PL[131*129];
  const int S = 129;
  int t = threadIdx.x, l = t & 63, w = t >> 6;
  int blk = blockIdx.x;
  int c = blk >> 4, b = blk & 15;        // 16 consecutive blocks share c (Khat L2 reuse)
  const float* xp = x   + ((size_t)b*CC + c)*(HH*WW);
  float*       yp = out + ((size_t)b*CC + c)*(HH*WW);
  Tw tw;  tw_init(tw, l);
  Tw2 t2; tw2_init(t2, l);
  int r6 = __brev((unsigned)l) >> 26;
  int l63 = l ^ 63;
  int p0 = __brev((unsigned)((64 - r6) & 63)) >> 26;

  // 1) x -> raw fp32 bits
  for (int i = t; i < HH*WW; i += 512){
    int p = i >> 7, q = i & 127;
    PL[p*S + q] = __float_as_uint(xp[i]);
  }
  __syncthreads();
  // 2) packed column forward FFTs (cols 2j,2j+1); separate; store half2 bins
#define SEPST16(Z, P, ROW) { \
  PL[(ROW)*S + q0]     = pkh2(Z.x + P.x, Z.y - P.y); \
  PL[(ROW)*S + q0 + 1] = pkh2(Z.y + P.y, P.x - Z.x); }

  for (int ji = 0; ji < 8; ++ji){
    int jj = w*8 + ji;                     // pair index 0..63
    int q0 = 2*jj;
    unsigned v0a = PL[l*S + q0],        v0b = PL[l*S + q0 + 1];
    unsigned v1a = PL[(l+64)*S + q0],   v1b = PL[(l+64)*S + q0 + 1];
    float2 x0 = make_float2(__uint_as_float(v0a), __uint_as_float(v0b));
    float2 x1 = make_float2(__uint_as_float(v1a), __uint_as_float(v1b));
    float2 x2, x3;
    fft256_fwd_padded(x0, x1, x2, x3, tw, l);
    float2 f0p = shfli(x0, p0);
    float2 f2p = shfli(x3, l63);
    float2 f1p = shfli(x1, l63);
    float2 f3p = shfli(x2, l63);
    if (r6 <= 32){ SEPST16(x0, f0p, r6); }          // bin 4r6    -> row r6
    if (r6 <= 31){
      SEPST16(x2, f2p, 33+r6);                      // bin 4r6+1
      SEPST16(x1, f1p, 66+r6);                      // bin 4r6+2
      SEPST16(x3, f3p, 99+r6);                      // bin 4r6+3
    }
  }
#undef SEPST16
  __syncthreads();
  // 3) row conv in packed fp16. 16 tasks/wave; wave0 task0 = rows (0,128).
  for (int k = 0; k < 16; ++k){
    int u = w + 8*k;
    if (w == 0 && k == 0){
      // packed real rows u=0 (pr=0) and u=128 (pr=32)
      unsigned a0 = PL[l],           a1 = PL[64 + l];
      unsigned c0 = PL[32*S + l],    c1 = PL[32*S + 64 + l];
      __half2 x0 = u2h2((a0 & 0xffffu) | (c0 << 16));
      __half2 x1 = u2h2((a1 & 0xffffu) | (c1 << 16));
      __half2 x2, x3;
      fft256_fwd_h2(x0, x1, x2, x3, t2);
      __half2 f0p = u2h2((unsigned)__shfl((int)h22u(x0), p0, 64));
      __half2 f2p = u2h2((unsigned)__shfl((int)h22u(x3), l63, 64));
      __half2 f1p = u2h2((unsigned)__shfl((int)h22u(x1), l63, 64));
      __half2 f3p = u2h2((unsigned)__shfl((int)h22u(x2), l63, 64));
      const uint2* k0p = (const uint2*)(Khat + (size_t)c*NF*FN);          // u=0
      const uint2* k1p = (const uint2*)(Khat + ((size_t)c*NF + 128)*FN);  // u=128
      const __half2 C1M1 = pk2h(1.0f, -1.0f);
      const __half2 CM11 = pk2h(-1.0f, 1.0f);
#define PKM(Z, P, OFF) { \
      __half2 A2_ = __hfma2(P, C1M1, Z); \
      __half2 B2_ = __hfma2(swap_h2(Z), C1M1, swap_h2(P)); \
      uint2 k0_ = k0p[OFF], k1_ = k1p[OFF]; \
      __half2 m0_ = cmulW_h2(A2_, u2h2(k0_.x), u2h2(k0_.y)); \
      __half2 m1_ = cmulW_h2(B2_, u2h2(k1_.x), u2h2(k1_.y)); \
      Z = __hfma2(swap_h2(m1_), CM11, m0_); }
      PKM(x0, f0p, l);
      PKM(x2, f2p, 128 + l);
      PKM(x1, f1p, 64 + l);
      PKM(x3, f3p, 192 + l);
#undef PKM
      fft256_inv_h2(x0, x1, x2, x3, t2, l);
      const __half2 H05 = pk2h(0.5f, 0.5f);   // extra 1/2 from this packing
      unsigned u0 = h22u(__hmul2(x0, H05));
      unsigned u1 = h22u(__hmul2(x1, H05));
      PL[l]             = u0 & 0xffffu;        // Y[0][l]   (real)
      PL[32*S + l]      = u0 >> 16;            // Y[128][l] (real)
      PL[64 + l]        = u1 & 0xffffu;
      PL[32*S + 64 + l] = u1 >> 16;
    } else {
      int pr = (u >> 2) + 33*(u & 3);
      __half2 x0 = u2h2(PL[pr*S + l]);
      __half2 x1 = u2h2(PL[pr*S + 64 + l]);
      __half2 x2, x3;
      fft256_fwd_h2(x0, x1, x2, x3, t2);
      const uint2* kp = (const uint2*)(Khat + ((size_t)c*NF + u)*FN);
      uint2 ka = kp[l], kb = kp[64 + l], kc = kp[128 + l], kd = kp[192 + l];
      x0 = cmulW_h2(x0, u2h2(ka.x), u2h2(ka.y));
      x1 = cmulW_h2(x1, u2h2(kb.x), u2h2(kb.y));
      x2 = cmulW_h2(x2, u2h2(kc.x), u2h2(kc.y));
      x3 = cmulW_h2(x3, u2h2(kd.x), u2h2(kd.y));
      fft256_inv_h2(x0, x1, x2, x3, t2, l);
      PL[pr*S + l]      = h22u(x0);   // SCL_DN already folded into K
      PL[pr*S + 64 + l] = h22u(x1);
    }
  }
  __syncthreads();
  // 4) packed column inverse (Hermitian gather by natural bin) + crop -> y bits
#define GATHV(X, ROWA, ROWB, COND) { \
  int row_ = (COND) ? (ROWA) : (ROWB); \
  float s_ = (COND) ? -1.0f : 1.0f; \
  unsigned ux_ = PL[row_*S + q0]; \
  unsigned uy_ = PL[row_*S + q0 + 1]; \
  X = make_float2(fmaf(s_, h2hi(uy_), h2lo(ux_)), \
                  fmaf(-s_, h2hi(ux_), h2lo(uy_))); }

  for (int ji = 0; ji < 8; ++ji){
    int jj = w*8 + ji;
    int q0 = 2*jj;
    float2 x0, x1, x2, x3;
    GATHV(x0, r6,    64-r6,  r6 <= 32);    // bins 4r6
    GATHV(x2, 33+r6, 162-r6, r6 <= 31);    // bins 4r6+1
    GATHV(x1, 66+r6, 129-r6, r6 <= 31);    // bins 4r6+2
    GATHV(x3, 99+r6, 96-r6,  r6 <= 31);    // bins 4r6+3
    fft256_inv_crop(x0, x1, x2, x3, tw, l);
    PL[l*S + q0]          = __float_as_uint(x0.x * SCL_UP);
    PL[l*S + q0 + 1]      = __float_as_uint(x0.y * SCL_UP);
    PL[(l+64)*S + q0]     = __float_as_uint(x1.x * SCL_UP);
    PL[(l+64)*S + q0 + 1] = __float_as_uint(x1.y * SCL_UP);
  }
#undef GATHV
  __syncthreads();
  // 5) out = y + x (coalesced)
  for (int i = t; i < HH*WW; i += 512){
    int p = i >> 7, q = i & 127;
    yp[i] = __uint_as_float(PL[p*S + q]) + xp[i];
  }
}

// ---------------------------------------------------------------------------
// Host launcher
// ---------------------------------------------------------------------------
extern "C" void kernel_launch(void* const* d_in, const int* in_sizes, int n_in,
                              void* d_out, int out_size, void* d_ws, size_t ws_size,
                              hipStream_t stream) {
  const float* x  = (const float*)d_in[0];
  const float* W1 = (const float*)d_in[1];
  const float* b1 = (const float*)d_in[2];
  const float* W2 = (const float*)d_in[3];
  const float* b2 = (const float*)d_in[4];
  float* out = (float*)d_out;

  float2* Khat = (float2*)d_ws;   // CC*NF*FN slots; fp16-split K after kprep_row

  kprep_col<<<CC*2, 512, 0, stream>>>(W1, b1, W2, b2, Khat);
  kprep_row<<<CC*4, 512, 0, stream>>>(Khat);
  fused_conv<<<CC*BB, 512, 0, stream>>>(x, Khat, out);
}